// Round 2
// baseline (812.860 us; speedup 1.0000x reference)
//
#include <hip/hip_runtime.h>

// LCT FK-migration: 3D FFT(512,256,256) -> Stolt trilinear resample -> 3D IFFT -> |.|^2
// Workspace layout (uses EXACTLY 512*256*256*8 = 268,435,456 B = 256 MiB):
//   V   @ ws+0          : 512*256*256 float2 (forward spectrum; only z<256 ever valid)
//   W   = V + 256*65536 : resampled spectrum, aliased onto V's (never-read) upper z-half.
// Twiddles live in a __device__ global (2 KiB), written each call by k_tw.
// Sparsity exploited: forward passes read only nonzero halves; resample gathers only
// unshifted z in [0,256); inverse z-pass reads/writes only z<256.

typedef float2 cpx;

__device__ float2 g_tw[256];   // exp(-2*pi*i*j/512), j in [0,256)

__device__ __forceinline__ cpx cadd(cpx a, cpx b){ return make_float2(a.x+b.x, a.y+b.y); }
__device__ __forceinline__ cpx csub(cpx a, cpx b){ return make_float2(a.x-b.x, a.y-b.y); }
__device__ __forceinline__ cpx cmul(cpx a, cpx b){ return make_float2(a.x*b.x - a.y*b.y, a.x*b.y + a.y*b.x); }

// ---------------- twiddle table (double-computed for accuracy) ----------------
__global__ void k_tw(){
    int j = threadIdx.x;                        // 256 threads
    double a = -2.0*3.14159265358979323846*(double)j/512.0;
    g_tw[j] = make_float2((float)cos(a), (float)sin(a));
}

// ---------------- fill corner: data = sqrt(relu(feat * (z/255)^2)) ----------------
__global__ __launch_bounds__(256) void k_fill(const float* __restrict__ in, cpx* __restrict__ V){
    int t = blockIdx.x*256 + threadIdx.x;       // 256*128*128 exactly
    int x = t & 127, y = (t >> 7) & 127, z = t >> 14;
    float g = (float)z*(1.0f/255.0f);
    float v = in[t]*g*g;
    v = v > 0.0f ? sqrtf(v) : 0.0f;
    V[(z << 16) + (y << 8) + x] = make_float2(v, 0.0f);
}

// ---------------- in-LDS FFT, layout s[line][elem], 2 lines of LEN, 256 thr ----------------
template<int L2LEN, bool INV>
__device__ __forceinline__ void fft_rows2(cpx* s, const cpx* ltw, int tid){
    const int LEN = 1 << L2LEN;
    #pragma unroll
    for (int st = 0; st < L2LEN; ++st){
        int lh = L2LEN - 1 - st;
        int half = 1 << lh;
        int tws = 512 >> (L2LEN - st);          // 512/m
        int l  = tid >> (L2LEN - 1);
        int bf = tid & ((LEN/2) - 1);
        int j  = bf & (half - 1);
        int i0 = ((bf >> lh) << (lh + 1)) | j;
        cpx u = s[l*LEN + i0], v = s[l*LEN + i0 + half];
        cpx w = ltw[j*tws];
        if (INV) w.y = -w.y;
        s[l*LEN + i0]        = cadd(u, v);
        s[l*LEN + i0 + half] = cmul(csub(u, v), w);
        __syncthreads();
    }
    for (int i = tid; i < 2*LEN; i += 256){     // bit-reversal -> natural order
        int l = i >> L2LEN, k = i & (LEN - 1);
        int r = __brev((unsigned)k) >> (32 - L2LEN);
        if (r > k){ cpx a = s[l*LEN + k]; s[l*LEN + k] = s[l*LEN + r]; s[l*LEN + r] = a; }
    }
    __syncthreads();
}

// ---------------- in-LDS FFT, layout s[elem*16 + col], 16 columns, 256 thr ----------------
template<int L2LEN, bool INV>
__device__ __forceinline__ void fft_cols16(cpx* s, const cpx* twp, int tid){
    const int LEN = 1 << L2LEN;
    const int NB = (LEN/2)*16;
    #pragma unroll
    for (int st = 0; st < L2LEN; ++st){
        int lh = L2LEN - 1 - st;
        int half = 1 << lh;
        int tws = 512 >> (L2LEN - st);
        for (int i = tid; i < NB; i += 256){
            int c = i & 15, bf = i >> 4;
            int j = bf & (half - 1);
            int i0 = ((bf >> lh) << (lh + 1)) | j;
            int i1 = i0 + half;
            cpx u = s[i0*16 + c], v = s[i1*16 + c];
            cpx w = twp[j*tws];
            if (INV) w.y = -w.y;
            s[i0*16 + c] = cadd(u, v);
            s[i1*16 + c] = cmul(csub(u, v), w);
        }
        __syncthreads();
    }
    for (int i = tid; i < LEN*16; i += 256){
        int c = i & 15, k = i >> 4;
        int r = __brev((unsigned)k) >> (32 - L2LEN);
        if (r > k){ cpx a = s[k*16 + c]; s[k*16 + c] = s[r*16 + c]; s[r*16 + c] = a; }
    }
    __syncthreads();
}

// ---------------- FFT along x (contiguous), lines (z<256, y<128), in-place ----------------
template<bool INV, bool HALF_IN>
__global__ __launch_bounds__(256) void k_fft_x(cpx* __restrict__ V){
    __shared__ cpx s[2*256];
    __shared__ cpx ltw[256];
    int tid = threadIdx.x;
    ltw[tid] = g_tw[tid];
    int line0 = blockIdx.x << 1;
    if (HALF_IN){
        int l = tid >> 7, e = tid & 127;
        int line = line0 + l;
        int base = ((line >> 7) << 16) + ((line & 127) << 8);
        s[l*256 + e]       = V[base + e];
        s[l*256 + e + 128] = make_float2(0.0f, 0.0f);
    } else {
        for (int i = tid; i < 512; i += 256){
            int l = i >> 8, e = i & 255;
            int line = line0 + l;
            int base = ((line >> 7) << 16) + ((line & 127) << 8);
            s[l*256 + e] = V[base + e];
        }
    }
    __syncthreads();
    fft_rows2<8, INV>(s, ltw, tid);
    for (int i = tid; i < 512; i += 256){
        int l = i >> 8, e = i & 255;
        int line = line0 + l;
        int base = ((line >> 7) << 16) + ((line & 127) << 8);
        V[base + e] = s[l*256 + e];
    }
}

// ---------------- final inverse x-FFT fused with |.|^2, crop x<128 ----------------
__global__ __launch_bounds__(256) void k_fft_x_inv_mag(const cpx* __restrict__ W,
                                                       float* __restrict__ out){
    __shared__ cpx s[2*256];
    __shared__ cpx ltw[256];
    int tid = threadIdx.x;
    ltw[tid] = g_tw[tid];
    int line0 = blockIdx.x << 1;
    for (int i = tid; i < 512; i += 256){
        int l = i >> 8, e = i & 255;
        int line = line0 + l;
        int base = ((line >> 7) << 16) + ((line & 127) << 8);
        s[l*256 + e] = W[base + e];
    }
    __syncthreads();
    fft_rows2<8, true>(s, ltw, tid);
    {
        int l = tid >> 7, e = tid & 127;
        int line = line0 + l;
        int z = line >> 7, y = line & 127;
        cpx v = s[l*256 + e];
        const float SC2 = (1.0f/33554432.0f)*(1.0f/33554432.0f);   // (1/(512*256*256))^2
        out[(z*128 + y)*128 + e] = (v.x*v.x + v.y*v.y)*SC2;
    }
}

// ---------------- FFT along y (stride 256), tile of 16 x, fixed z<256, in-place ----------------
template<bool INV, bool HALF_IN, bool HALF_OUT>
__global__ __launch_bounds__(256) void k_fft_y(cpx* __restrict__ V){
    __shared__ cpx s[256*16];
    __shared__ cpx ltw[256];
    int tid = threadIdx.x;
    ltw[tid] = g_tw[tid];
    int z  = blockIdx.x >> 4;
    int x0 = (blockIdx.x & 15) << 4;
    int base = (z << 16) + x0;
    const int YIN = HALF_IN ? 128 : 256;
    for (int i = tid; i < YIN*16; i += 256){
        int c = i & 15, e = i >> 4;
        s[e*16 + c] = V[base + (e << 8) + c];
    }
    if (HALF_IN){
        for (int i = tid; i < 128*16; i += 256){
            int c = i & 15, e = (i >> 4) + 128;
            s[e*16 + c] = make_float2(0.0f, 0.0f);
        }
    }
    __syncthreads();
    fft_cols16<8, INV>(s, ltw, tid);
    const int YOUT = HALF_OUT ? 128 : 256;
    for (int i = tid; i < YOUT*16; i += 256){
        int c = i & 15, e = i >> 4;
        V[base + (e << 8) + c] = s[e*16 + c];
    }
}

// ---------------- FFT along z (stride 65536), tile of 16 x, fixed y, in-place ----------------
template<bool INV, bool HALF_IN, bool HALF_OUT>
__global__ __launch_bounds__(256) void k_fft_z(cpx* __restrict__ V){
    __shared__ cpx s[512*16];                    // 64 KiB exactly; twiddles from global (L2-resident)
    int tid = threadIdx.x;
    int y  = blockIdx.x >> 4;
    int x0 = (blockIdx.x & 15) << 4;
    int base = (y << 8) + x0;
    const int ZIN = HALF_IN ? 256 : 512;
    for (int i = tid; i < ZIN*16; i += 256){
        int c = i & 15, e = i >> 4;
        s[e*16 + c] = V[base + (e << 16) + c];
    }
    if (HALF_IN){
        for (int i = tid; i < 256*16; i += 256){
            int c = i & 15, e = (i >> 4) + 256;
            s[e*16 + c] = make_float2(0.0f, 0.0f);
        }
    }
    __syncthreads();
    fft_cols16<9, INV>(s, g_tw, tid);
    const int ZOUT = HALF_OUT ? 256 : 512;
    for (int i = tid; i < ZOUT*16; i += 256){
        int c = i & 15, e = i >> 4;
        V[base + (e << 16) + c] = s[e*16 + c];
    }
}

// ---------------- Stolt resample (fftshift + grid_sample + zero/scale + ifftshift fused) ----------------
// Destination index zd in [0,256) only (rest is zero & never read by the inverse pass).
__global__ __launch_bounds__(256) void k_resample(const cpx* __restrict__ V, cpx* __restrict__ W){
    int t = blockIdx.x*256 + threadIdx.x;        // 256*256*256 exactly
    int xd = t & 255, yd = (t >> 8) & 255, zd = t >> 16;
    int zs = (zd + 256) & 511;                   // position in fftshifted space
    cpx res = make_float2(0.0f, 0.0f);
    if (zs > 256){                               // t[:, :M+1] = 0 keeps only zs in [257,511]
        int ys = (yd + 128) & 255, xs = (xd + 128) & 255;
        float gz = (float)(zs - 256)*(1.0f/256.0f);
        float gy = (float)(ys - 128)*(1.0f/128.0f);
        float gx = (float)(xs - 128)*(1.0f/128.0f);
        float gzn = sqrtf(0.1024f*(gx*gx + gy*gy) + gz*gz);
        // grid_sample coords, align_corners=False (exact reference arithmetic)
        float ix = ((gx + 1.0f)*256.0f - 1.0f)*0.5f;
        float iy = ((gy + 1.0f)*256.0f - 1.0f)*0.5f;
        float iz = ((gzn + 1.0f)*512.0f - 1.0f)*0.5f;
        float fix = floorf(ix), fiy = floorf(iy), fiz = floorf(iz);
        int ix0 = (int)fix, iy0 = (int)fiy, iz0 = (int)fiz;
        float fx = ix - fix, fy = iy - fiy, fz = iz - fiz;
        float ar = 0.0f, ai = 0.0f;
        #pragma unroll
        for (int dz = 0; dz < 2; ++dz){
            int zi = iz0 + dz;
            if (zi < 0 || zi >= 512) continue;
            float wz = dz ? fz : 1.0f - fz;
            int zu = (zi + 256) & 511;           // shifted -> unshifted (lands in z<256)
            #pragma unroll
            for (int dy = 0; dy < 2; ++dy){
                int yi = iy0 + dy;
                if (yi < 0 || yi >= 256) continue;
                float wy = dy ? fy : 1.0f - fy;
                int yu = (yi + 128) & 255;
                int rowbase = (zu << 16) + (yu << 8);
                #pragma unroll
                for (int dx = 0; dx < 2; ++dx){
                    int xi = ix0 + dx;
                    if (xi < 0 || xi >= 256) continue;
                    float wx = dx ? fx : 1.0f - fx;
                    int xu = (xi + 128) & 255;
                    cpx v = V[rowbase + xu];
                    float w = wx*wy*wz;
                    ar += v.x*w; ai += v.y*w;
                }
            }
        }
        float sc = gz/(gzn + 1e-8f);             // |gz|/(gznew+eps), gz>0 here
        res = make_float2(ar*sc, ai*sc);
    }
    W[t] = res;
}

extern "C" void kernel_launch(void* const* d_in, const int* in_sizes, int n_in,
                              void* d_out, int out_size, void* d_ws, size_t ws_size,
                              hipStream_t stream){
    const float* feat = (const float*)d_in[0];   // [1,1,256,128,128] f32; tbes=0, tens=256 fixed
    float* out = (float*)d_out;                  // [1,1,256,128,128] f32

    const size_t WS_NEED = (size_t)512*256*256*8;   // 268,435,456 B exactly
    if (ws_size < WS_NEED){
        // Clean diagnostic path instead of a page fault: zero output and bail.
        hipMemsetAsync(d_out, 0, (size_t)out_size*sizeof(float), stream);
        return;
    }
    cpx* V = (cpx*)d_ws;
    cpx* W = V + (size_t)256*65536;              // alias: upper z-half of V

    k_tw<<<1, 256, 0, stream>>>();
    k_fill<<<16384, 256, 0, stream>>>(feat, V);
    // forward FFT (nonzero-region passes only)
    k_fft_x<false, true ><<<16384, 256, 0, stream>>>(V);            // lines z<256,y<128; x<128 in
    k_fft_y<false, true, false><<<4096, 256, 0, stream>>>(V);       // z<256; y<128 in, full y out
    k_fft_z<false, true, true ><<<4096, 256, 0, stream>>>(V);       // z<256 in, z<256 out (upper never read)
    // Stolt resample into W (= V upper half); writes zd<256 fully
    k_resample<<<65536, 256, 0, stream>>>(V, W);
    // inverse FFT + crop
    k_fft_z<true, true, true ><<<4096, 256, 0, stream>>>(W);        // z<256 in (rest zero), z<256 out
    k_fft_y<true, false, true><<<4096, 256, 0, stream>>>(W);        // full y in, y<128 out
    k_fft_x_inv_mag<<<16384, 256, 0, stream>>>(W, out);             // full x in, |.|^2 to out x<128
}

// Round 3
// 477.680 us; speedup vs baseline: 1.7017x; 1.7017x over previous
//
#include <hip/hip_runtime.h>

// LCT FK-migration: 3D FFT(512,256,256) -> Stolt trilinear resample -> 3D IFFT -> |.|^2
// Workspace layout (uses EXACTLY 512*256*256*8 = 268,435,456 B = 256 MiB):
//   V   @ ws+0          : 512*256*256 float2 (forward spectrum; only z<256 ever valid)
//   W   = V + 256*65536 : resampled spectrum, aliased onto V's (never-read) upper z-half.
// Twiddles in __device__ global g_tw[512] = W_512^k, written each call by k_tw.
// Sparsity: forward passes read only nonzero halves; resample gathers only unshifted
// z in [0,256); inverse z-pass reads/writes only z<256.
// Round-3 change: z-FFT = 3 radix-8 DIF stages (register butterflies), y-FFT = 4
// radix-4 DIF stages. 1024-thr blocks, digit-reversal folded into the output write.

typedef float2 cpx;

__device__ float2 g_tw[512];   // exp(-2*pi*i*k/512), k in [0,512)

__device__ __forceinline__ cpx cadd(cpx a, cpx b){ return make_float2(a.x+b.x, a.y+b.y); }
__device__ __forceinline__ cpx csub(cpx a, cpx b){ return make_float2(a.x-b.x, a.y-b.y); }
__device__ __forceinline__ cpx cmul(cpx a, cpx b){ return make_float2(a.x*b.x - a.y*b.y, a.x*b.y + a.y*b.x); }

// ---------------- twiddle table (double-computed for accuracy) ----------------
__global__ void k_tw(){
    int j = threadIdx.x;                        // 512 threads
    double a = -2.0*3.14159265358979323846*(double)j/512.0;
    g_tw[j] = make_float2((float)cos(a), (float)sin(a));
}

// x *= W_512^k (forward) or W_512^-k (inverse); caller guarantees k in [0,512)
template<bool INV>
__device__ __forceinline__ cpx twmul(cpx a, int k){
    cpx w = g_tw[k & 511];
    if (INV) w.y = -w.y;
    return cmul(a, w);
}

// ---------------- radix-4 DIF butterfly (in-register) ----------------
template<bool INV>
__device__ __forceinline__ void dft4(cpx* x){
    cpx e0 = cadd(x[0], x[2]), e1 = csub(x[0], x[2]);
    cpx o0 = cadd(x[1], x[3]), o1 = csub(x[1], x[3]);
    x[0] = cadd(e0, o0);
    x[2] = csub(e0, o0);
    if (!INV){ x[1] = make_float2(e1.x + o1.y, e1.y - o1.x);     // e1 - i*o1
               x[3] = make_float2(e1.x - o1.y, e1.y + o1.x); }   // e1 + i*o1
    else     { x[1] = make_float2(e1.x - o1.y, e1.y + o1.x);
               x[3] = make_float2(e1.x + o1.y, e1.y - o1.x); }
}

// ---------------- radix-8 DIF butterfly (in-register) ----------------
template<bool INV>
__device__ __forceinline__ void dft8(cpx* x){
    const float s = 0.70710678118654752440f;
    cpx e0 = cadd(x[0], x[4]), e2 = csub(x[0], x[4]);
    cpx e1 = cadd(x[2], x[6]), e3 = csub(x[2], x[6]);
    cpx E0 = cadd(e0, e1), E2 = csub(e0, e1);
    cpx E1, E3;
    if (!INV){ E1 = make_float2(e2.x + e3.y, e2.y - e3.x);       // e2 - i*e3
               E3 = make_float2(e2.x - e3.y, e2.y + e3.x); }
    else     { E1 = make_float2(e2.x - e3.y, e2.y + e3.x);
               E3 = make_float2(e2.x + e3.y, e2.y - e3.x); }
    cpx o0 = cadd(x[1], x[5]), o2 = csub(x[1], x[5]);
    cpx o1 = cadd(x[3], x[7]), o3 = csub(x[3], x[7]);
    cpx O0 = cadd(o0, o1), O2 = csub(o0, o1);
    cpx O1, O3;
    if (!INV){ O1 = make_float2(o2.x + o3.y, o2.y - o3.x);
               O3 = make_float2(o2.x - o3.y, o2.y + o3.x); }
    else     { O1 = make_float2(o2.x - o3.y, o2.y + o3.x);
               O3 = make_float2(o2.x + o3.y, o2.y - o3.x); }
    cpx W1, W2, W3;
    if (!INV){
        W1 = make_float2(s*(O1.x + O1.y), s*(O1.y - O1.x));      // ×(s,-s)
        W2 = make_float2(O2.y, -O2.x);                           // ×(-i)
        W3 = make_float2(s*(O3.y - O3.x), -s*(O3.x + O3.y));     // ×(-s,-s)
    } else {
        W1 = make_float2(s*(O1.x - O1.y), s*(O1.x + O1.y));      // ×(s,s)
        W2 = make_float2(-O2.y, O2.x);                           // ×(+i)
        W3 = make_float2(-s*(O3.x + O3.y), s*(O3.x - O3.y));     // ×(-s,s)
    }
    x[0] = cadd(E0, O0); x[4] = csub(E0, O0);
    x[1] = cadd(E1, W1); x[5] = csub(E1, W1);
    x[2] = cadd(E2, W2); x[6] = csub(E2, W2);
    x[3] = cadd(E3, W3); x[7] = csub(E3, W3);
}

// ---------------- fill corner: data = sqrt(relu(feat * (z/255)^2)) ----------------
__global__ __launch_bounds__(256) void k_fill(const float* __restrict__ in, cpx* __restrict__ V){
    int t = blockIdx.x*256 + threadIdx.x;       // 256*128*128 exactly
    int x = t & 127, y = (t >> 7) & 127, z = t >> 14;
    float g = (float)z*(1.0f/255.0f);
    float v = in[t]*g*g;
    v = v > 0.0f ? sqrtf(v) : 0.0f;
    V[(z << 16) + (y << 8) + x] = make_float2(v, 0.0f);
}

// ---------------- in-LDS radix-2 FFT, layout s[line][elem], 2 lines of 256 ----------------
template<bool INV>
__device__ __forceinline__ void fft_rows2(cpx* s, const cpx* ltw, int tid){
    const int L2LEN = 8, LEN = 256;
    #pragma unroll
    for (int st = 0; st < L2LEN; ++st){
        int lh = L2LEN - 1 - st;
        int half = 1 << lh;
        int tws = 512 >> (L2LEN - st);
        int l  = tid >> (L2LEN - 1);
        int bf = tid & ((LEN/2) - 1);
        int j  = bf & (half - 1);
        int i0 = ((bf >> lh) << (lh + 1)) | j;
        cpx u = s[l*LEN + i0], v = s[l*LEN + i0 + half];
        cpx w = ltw[j*tws];
        if (INV) w.y = -w.y;
        s[l*LEN + i0]        = cadd(u, v);
        s[l*LEN + i0 + half] = cmul(csub(u, v), w);
        __syncthreads();
    }
    for (int i = tid; i < 2*LEN; i += 256){     // bit-reversal -> natural order
        int l = i >> L2LEN, k = i & (LEN - 1);
        int r = __brev((unsigned)k) >> (32 - L2LEN);
        if (r > k){ cpx a = s[l*LEN + k]; s[l*LEN + k] = s[l*LEN + r]; s[l*LEN + r] = a; }
    }
    __syncthreads();
}

// ---------------- FFT along x (contiguous), lines (z<256, y<128), in-place ----------------
template<bool INV, bool HALF_IN>
__global__ __launch_bounds__(256) void k_fft_x(cpx* __restrict__ V){
    __shared__ cpx s[2*256];
    __shared__ cpx ltw[256];
    int tid = threadIdx.x;
    ltw[tid] = g_tw[tid];
    int line0 = blockIdx.x << 1;
    if (HALF_IN){
        int l = tid >> 7, e = tid & 127;
        int line = line0 + l;
        int base = ((line >> 7) << 16) + ((line & 127) << 8);
        s[l*256 + e]       = V[base + e];
        s[l*256 + e + 128] = make_float2(0.0f, 0.0f);
    } else {
        for (int i = tid; i < 512; i += 256){
            int l = i >> 8, e = i & 255;
            int line = line0 + l;
            int base = ((line >> 7) << 16) + ((line & 127) << 8);
            s[l*256 + e] = V[base + e];
        }
    }
    __syncthreads();
    fft_rows2<INV>(s, ltw, tid);
    for (int i = tid; i < 512; i += 256){
        int l = i >> 8, e = i & 255;
        int line = line0 + l;
        int base = ((line >> 7) << 16) + ((line & 127) << 8);
        V[base + e] = s[l*256 + e];
    }
}

// ---------------- final inverse x-FFT fused with |.|^2, crop x<128 ----------------
__global__ __launch_bounds__(256) void k_fft_x_inv_mag(const cpx* __restrict__ W,
                                                       float* __restrict__ out){
    __shared__ cpx s[2*256];
    __shared__ cpx ltw[256];
    int tid = threadIdx.x;
    ltw[tid] = g_tw[tid];
    int line0 = blockIdx.x << 1;
    for (int i = tid; i < 512; i += 256){
        int l = i >> 8, e = i & 255;
        int line = line0 + l;
        int base = ((line >> 7) << 16) + ((line & 127) << 8);
        s[l*256 + e] = W[base + e];
    }
    __syncthreads();
    fft_rows2<true>(s, ltw, tid);
    {
        int l = tid >> 7, e = tid & 127;
        int line = line0 + l;
        int z = line >> 7, y = line & 127;
        cpx v = s[l*256 + e];
        const float SC2 = (1.0f/33554432.0f)*(1.0f/33554432.0f);   // (1/(512*256*256))^2
        out[(z*128 + y)*128 + e] = (v.x*v.x + v.y*v.y)*SC2;
    }
}

// ---------------- FFT along y: 256 pts = 4 radix-4 DIF stages, tile 16 x, fixed z ----------------
// LDS layout s[e*16 + c]; digit-reversal (base-4) folded into output write.
template<bool INV, bool HALF_IN, bool HALF_OUT>
__global__ __launch_bounds__(1024) void k_fft_y(cpx* __restrict__ V){
    __shared__ cpx s[256*16];                   // 32 KiB
    int tid = threadIdx.x;
    int z  = blockIdx.x >> 4;
    int x0 = (blockIdx.x & 15) << 4;
    int base = (z << 16) + x0;
    const int YIN = HALF_IN ? 128 : 256;
    for (int i = tid; i < YIN*16; i += 1024){
        int c = i & 15, e = i >> 4;
        s[e*16 + c] = V[base + (e << 8) + c];
    }
    if (HALF_IN){
        for (int i = tid; i < 128*16; i += 1024){
            int c = i & 15, e = (i >> 4) + 128;
            s[e*16 + c] = make_float2(0.0f, 0.0f);
        }
    }
    __syncthreads();
    int c = tid & 15, idx = tid >> 4;           // idx in [0,64): one radix-4 butterfly per stage
    cpx x[4];
    // stage 0: L=256, j=idx, stride 64, tw W_512^{2*j*r}
    {
        int j = idx;
        #pragma unroll
        for (int t = 0; t < 4; ++t) x[t] = s[(j + (t << 6))*16 + c];
        dft4<INV>(x);
        #pragma unroll
        for (int r = 1; r < 4; ++r) x[r] = twmul<INV>(x[r], 2*j*r);
        #pragma unroll
        for (int r = 0; r < 4; ++r) s[(j + (r << 6))*16 + c] = x[r];
    }
    __syncthreads();
    // stage 1: L=64, j=idx&15, g=(idx>>4)*64, stride 16, tw W_512^{8*j*r}
    {
        int j = idx & 15, g = (idx >> 4) << 6;
        #pragma unroll
        for (int t = 0; t < 4; ++t) x[t] = s[(g + j + (t << 4))*16 + c];
        dft4<INV>(x);
        #pragma unroll
        for (int r = 1; r < 4; ++r) x[r] = twmul<INV>(x[r], 8*j*r);
        #pragma unroll
        for (int r = 0; r < 4; ++r) s[(g + j + (r << 4))*16 + c] = x[r];
    }
    __syncthreads();
    // stage 2: L=16, j=idx&3, g=(idx>>2)*16, stride 4, tw W_512^{32*j*r}
    {
        int j = idx & 3, g = (idx >> 2) << 4;
        #pragma unroll
        for (int t = 0; t < 4; ++t) x[t] = s[(g + j + (t << 2))*16 + c];
        dft4<INV>(x);
        #pragma unroll
        for (int r = 1; r < 4; ++r) x[r] = twmul<INV>(x[r], 32*j*r);
        #pragma unroll
        for (int r = 0; r < 4; ++r) s[(g + j + (r << 2))*16 + c] = x[r];
    }
    __syncthreads();
    // stage 3: L=4, g=idx*4, stride 1, no twiddle
    {
        int g = idx << 2;
        #pragma unroll
        for (int t = 0; t < 4; ++t) x[t] = s[(g + t)*16 + c];
        dft4<INV>(x);
        #pragma unroll
        for (int r = 0; r < 4; ++r) s[(g + r)*16 + c] = x[r];
    }
    __syncthreads();
    const int YOUT = HALF_OUT ? 128 : 256;
    for (int i = tid; i < YOUT*16; i += 1024){
        int cc = i & 15, e = i >> 4;
        int p = ((e & 3) << 6) | (((e >> 2) & 3) << 4) | (((e >> 4) & 3) << 2) | (e >> 6);
        V[base + (e << 8) + cc] = s[p*16 + cc];
    }
}

// ---------------- FFT along z: 512 pts = 3 radix-8 DIF stages, tile 16 x, fixed y ----------------
template<bool INV, bool HALF_IN, bool HALF_OUT>
__global__ __launch_bounds__(1024) void k_fft_z(cpx* __restrict__ V){
    __shared__ cpx s[512*16];                   // 64 KiB
    int tid = threadIdx.x;
    int y  = blockIdx.x >> 4;
    int x0 = (blockIdx.x & 15) << 4;
    int base = (y << 8) + x0;
    const int ZIN = HALF_IN ? 256 : 512;
    for (int i = tid; i < ZIN*16; i += 1024){
        int c = i & 15, e = i >> 4;
        s[e*16 + c] = V[base + (e << 16) + c];
    }
    if (HALF_IN){
        for (int i = tid; i < 256*16; i += 1024){
            int c = i & 15, e = (i >> 4) + 256;
            s[e*16 + c] = make_float2(0.0f, 0.0f);
        }
    }
    __syncthreads();
    int c = tid & 15, idx = tid >> 4;           // idx in [0,64): one radix-8 butterfly per stage
    cpx x[8];
    // stage 0: L=512, j=idx, stride 64, tw W_512^{j*r}
    {
        int j = idx;
        #pragma unroll
        for (int t = 0; t < 8; ++t) x[t] = s[(j + (t << 6))*16 + c];
        dft8<INV>(x);
        #pragma unroll
        for (int r = 1; r < 8; ++r) x[r] = twmul<INV>(x[r], j*r);
        #pragma unroll
        for (int r = 0; r < 8; ++r) s[(j + (r << 6))*16 + c] = x[r];
    }
    __syncthreads();
    // stage 1: L=64, j=idx&7, g=(idx>>3)*64, stride 8, tw W_512^{8*j*r}
    {
        int j = idx & 7, g = (idx >> 3) << 6;
        #pragma unroll
        for (int t = 0; t < 8; ++t) x[t] = s[(g + j + (t << 3))*16 + c];
        dft8<INV>(x);
        #pragma unroll
        for (int r = 1; r < 8; ++r) x[r] = twmul<INV>(x[r], 8*j*r);
        #pragma unroll
        for (int r = 0; r < 8; ++r) s[(g + j + (r << 3))*16 + c] = x[r];
    }
    __syncthreads();
    // stage 2: L=8, g=idx*8, stride 1, no twiddle
    {
        int g = idx << 3;
        #pragma unroll
        for (int t = 0; t < 8; ++t) x[t] = s[(g + t)*16 + c];
        dft8<INV>(x);
        #pragma unroll
        for (int r = 0; r < 8; ++r) s[(g + r)*16 + c] = x[r];
    }
    __syncthreads();
    const int ZOUT = HALF_OUT ? 256 : 512;
    for (int i = tid; i < ZOUT*16; i += 1024){
        int cc = i & 15, e = i >> 4;
        int p = ((e & 7) << 6) | (e & 56) | (e >> 6);   // base-8 digit reversal of 9 bits
        V[base + (e << 16) + cc] = s[p*16 + cc];
    }
}

// ---------------- Stolt resample (fftshift + grid_sample + zero/scale + ifftshift fused) ----------------
__global__ __launch_bounds__(256) void k_resample(const cpx* __restrict__ V, cpx* __restrict__ W){
    int t = blockIdx.x*256 + threadIdx.x;        // 256*256*256 exactly
    int xd = t & 255, yd = (t >> 8) & 255, zd = t >> 16;
    int zs = (zd + 256) & 511;                   // position in fftshifted space
    cpx res = make_float2(0.0f, 0.0f);
    if (zs > 256){                               // t[:, :M+1] = 0 keeps only zs in [257,511]
        int ys = (yd + 128) & 255, xs = (xd + 128) & 255;
        float gz = (float)(zs - 256)*(1.0f/256.0f);
        float gy = (float)(ys - 128)*(1.0f/128.0f);
        float gx = (float)(xs - 128)*(1.0f/128.0f);
        float gzn = sqrtf(0.1024f*(gx*gx + gy*gy) + gz*gz);
        float ix = ((gx + 1.0f)*256.0f - 1.0f)*0.5f;
        float iy = ((gy + 1.0f)*256.0f - 1.0f)*0.5f;
        float iz = ((gzn + 1.0f)*512.0f - 1.0f)*0.5f;
        float fix = floorf(ix), fiy = floorf(iy), fiz = floorf(iz);
        int ix0 = (int)fix, iy0 = (int)fiy, iz0 = (int)fiz;
        float fx = ix - fix, fy = iy - fiy, fz = iz - fiz;
        float ar = 0.0f, ai = 0.0f;
        #pragma unroll
        for (int dz = 0; dz < 2; ++dz){
            int zi = iz0 + dz;
            if (zi < 0 || zi >= 512) continue;
            float wz = dz ? fz : 1.0f - fz;
            int zu = (zi + 256) & 511;           // shifted -> unshifted (lands in z<256)
            #pragma unroll
            for (int dy = 0; dy < 2; ++dy){
                int yi = iy0 + dy;
                if (yi < 0 || yi >= 256) continue;
                float wy = dy ? fy : 1.0f - fy;
                int yu = (yi + 128) & 255;
                int rowbase = (zu << 16) + (yu << 8);
                #pragma unroll
                for (int dx = 0; dx < 2; ++dx){
                    int xi = ix0 + dx;
                    if (xi < 0 || xi >= 256) continue;
                    float wx = dx ? fx : 1.0f - fx;
                    int xu = (xi + 128) & 255;
                    cpx v = V[rowbase + xu];
                    float w = wx*wy*wz;
                    ar += v.x*w; ai += v.y*w;
                }
            }
        }
        float sc = gz/(gzn + 1e-8f);             // |gz|/(gznew+eps), gz>0 here
        res = make_float2(ar*sc, ai*sc);
    }
    W[t] = res;
}

extern "C" void kernel_launch(void* const* d_in, const int* in_sizes, int n_in,
                              void* d_out, int out_size, void* d_ws, size_t ws_size,
                              hipStream_t stream){
    const float* feat = (const float*)d_in[0];   // [1,1,256,128,128] f32; tbes=0, tens=256 fixed
    float* out = (float*)d_out;                  // [1,1,256,128,128] f32

    const size_t WS_NEED = (size_t)512*256*256*8;   // 268,435,456 B exactly
    if (ws_size < WS_NEED){
        hipMemsetAsync(d_out, 0, (size_t)out_size*sizeof(float), stream);
        return;
    }
    cpx* V = (cpx*)d_ws;
    cpx* W = V + (size_t)256*65536;              // alias: upper z-half of V

    k_tw<<<1, 512, 0, stream>>>();
    k_fill<<<16384, 256, 0, stream>>>(feat, V);
    // forward FFT (nonzero-region passes only)
    k_fft_x<false, true ><<<16384, 256, 0, stream>>>(V);            // lines z<256,y<128; x<128 in
    k_fft_y<false, true, false><<<4096, 1024, 0, stream>>>(V);      // z<256; y<128 in, full y out
    k_fft_z<false, true, true ><<<4096, 1024, 0, stream>>>(V);      // z<256 in, z<256 out
    // Stolt resample into W (= V upper half); writes zd<256 fully
    k_resample<<<65536, 256, 0, stream>>>(V, W);
    // inverse FFT + crop
    k_fft_z<true, true, true ><<<4096, 1024, 0, stream>>>(W);       // z<256 in (rest zero), z<256 out
    k_fft_y<true, false, true><<<4096, 1024, 0, stream>>>(W);       // full y in, y<128 out
    k_fft_x_inv_mag<<<16384, 256, 0, stream>>>(W, out);             // full x in, |.|^2 to out x<128
}

// Round 4
// 398.691 us; speedup vs baseline: 2.0388x; 1.1981x over previous
//
#include <hip/hip_runtime.h>

// LCT FK-migration: 3D FFT(512,256,256) -> Stolt trilinear resample -> 3D IFFT -> |.|^2
// Single 256 MiB workspace buffer V = [512][256][256] cpx, flat (z<<16)+(y<<8)+x.
// Forward spectrum is stored FFTSHIFTED (shift folded into forward output perms):
//   x,y: position (k+128)&255 ; z: bins 0..255 stored at planes 256..511.
// Resample gathers directly in shifted coords (contiguous float4 x-pairs, branchless),
// writes natural-order result into planes 0..255 (aliased, disjoint from source).
// Inverse FFT chain (z,y,x) runs on planes 0..255 and crops to [256,128,128].

typedef float2 cpx;

__device__ float2 g_tw[512];   // exp(-2*pi*i*k/512), k in [0,512)

__device__ __forceinline__ cpx cadd(cpx a, cpx b){ return make_float2(a.x+b.x, a.y+b.y); }
__device__ __forceinline__ cpx csub(cpx a, cpx b){ return make_float2(a.x-b.x, a.y-b.y); }
__device__ __forceinline__ cpx cmul(cpx a, cpx b){ return make_float2(a.x*b.x - a.y*b.y, a.x*b.y + a.y*b.x); }

// ---------------- twiddle table (double-computed for accuracy) ----------------
__global__ void k_tw(){
    int j = threadIdx.x;                        // 512 threads
    double a = -2.0*3.14159265358979323846*(double)j/512.0;
    g_tw[j] = make_float2((float)cos(a), (float)sin(a));
}

template<bool INV>
__device__ __forceinline__ cpx twmul(cpx a, int k){
    cpx w = g_tw[k & 511];
    if (INV) w.y = -w.y;
    return cmul(a, w);
}

// ---------------- radix-4 DIF butterfly (in-register) ----------------
template<bool INV>
__device__ __forceinline__ void dft4(cpx* x){
    cpx e0 = cadd(x[0], x[2]), e1 = csub(x[0], x[2]);
    cpx o0 = cadd(x[1], x[3]), o1 = csub(x[1], x[3]);
    x[0] = cadd(e0, o0);
    x[2] = csub(e0, o0);
    if (!INV){ x[1] = make_float2(e1.x + o1.y, e1.y - o1.x);
               x[3] = make_float2(e1.x - o1.y, e1.y + o1.x); }
    else     { x[1] = make_float2(e1.x - o1.y, e1.y + o1.x);
               x[3] = make_float2(e1.x + o1.y, e1.y - o1.x); }
}

// ---------------- radix-8 DIF butterfly (in-register) ----------------
template<bool INV>
__device__ __forceinline__ void dft8(cpx* x){
    const float s = 0.70710678118654752440f;
    cpx e0 = cadd(x[0], x[4]), e2 = csub(x[0], x[4]);
    cpx e1 = cadd(x[2], x[6]), e3 = csub(x[2], x[6]);
    cpx E0 = cadd(e0, e1), E2 = csub(e0, e1);
    cpx E1, E3;
    if (!INV){ E1 = make_float2(e2.x + e3.y, e2.y - e3.x);
               E3 = make_float2(e2.x - e3.y, e2.y + e3.x); }
    else     { E1 = make_float2(e2.x - e3.y, e2.y + e3.x);
               E3 = make_float2(e2.x + e3.y, e2.y - e3.x); }
    cpx o0 = cadd(x[1], x[5]), o2 = csub(x[1], x[5]);
    cpx o1 = cadd(x[3], x[7]), o3 = csub(x[3], x[7]);
    cpx O0 = cadd(o0, o1), O2 = csub(o0, o1);
    cpx O1, O3;
    if (!INV){ O1 = make_float2(o2.x + o3.y, o2.y - o3.x);
               O3 = make_float2(o2.x - o3.y, o2.y + o3.x); }
    else     { O1 = make_float2(o2.x - o3.y, o2.y + o3.x);
               O3 = make_float2(o2.x + o3.y, o2.y - o3.x); }
    cpx W1, W2, W3;
    if (!INV){
        W1 = make_float2(s*(O1.x + O1.y), s*(O1.y - O1.x));
        W2 = make_float2(O2.y, -O2.x);
        W3 = make_float2(s*(O3.y - O3.x), -s*(O3.x + O3.y));
    } else {
        W1 = make_float2(s*(O1.x - O1.y), s*(O1.x + O1.y));
        W2 = make_float2(-O2.y, O2.x);
        W3 = make_float2(-s*(O3.x + O3.y), s*(O3.x - O3.y));
    }
    x[0] = cadd(E0, O0); x[4] = csub(E0, O0);
    x[1] = cadd(E1, W1); x[5] = csub(E1, W1);
    x[2] = cadd(E2, W2); x[6] = csub(E2, W2);
    x[3] = cadd(E3, W3); x[7] = csub(E3, W3);
}

// ---------------- in-LDS radix-2 FFT, layout s[line][elem], 2 lines of 256 ----------------
template<bool INV>
__device__ __forceinline__ void fft_rows2(cpx* s, const cpx* ltw, int tid){
    const int L2LEN = 8, LEN = 256;
    #pragma unroll
    for (int st = 0; st < L2LEN; ++st){
        int lh = L2LEN - 1 - st;
        int half = 1 << lh;
        int tws = 512 >> (L2LEN - st);
        int l  = tid >> (L2LEN - 1);
        int bf = tid & ((LEN/2) - 1);
        int j  = bf & (half - 1);
        int i0 = ((bf >> lh) << (lh + 1)) | j;
        cpx u = s[l*LEN + i0], v = s[l*LEN + i0 + half];
        cpx w = ltw[j*tws];
        if (INV) w.y = -w.y;
        s[l*LEN + i0]        = cadd(u, v);
        s[l*LEN + i0 + half] = cmul(csub(u, v), w);
        __syncthreads();
    }
    for (int i = tid; i < 2*LEN; i += 256){     // bit-reversal -> natural order
        int l = i >> L2LEN, k = i & (LEN - 1);
        int r = __brev((unsigned)k) >> (32 - L2LEN);
        if (r > k){ cpx a = s[l*LEN + k]; s[l*LEN + k] = s[l*LEN + r]; s[l*LEN + r] = a; }
    }
    __syncthreads();
}

// ---------------- forward x-FFT fused with fill (window+sqrt), shifted-x output ----------------
__global__ __launch_bounds__(256) void k_fft_x_fill(const float* __restrict__ feat, cpx* __restrict__ V){
    __shared__ cpx s[2*256];
    __shared__ cpx ltw[256];
    int tid = threadIdx.x;
    ltw[tid] = g_tw[tid];
    int line0 = blockIdx.x << 1;                 // line = z*128 + y, z<256, y<128
    {
        int l = tid >> 7, e = tid & 127;
        int line = line0 + l;
        int z = line >> 7;
        float g = (float)z*(1.0f/255.0f);
        float v = feat[(line << 7) + e]*g*g;     // feat[z][y][x]
        v = v > 0.0f ? sqrtf(v) : 0.0f;
        s[l*256 + e]       = make_float2(v, 0.0f);
        s[l*256 + e + 128] = make_float2(0.0f, 0.0f);
    }
    __syncthreads();
    fft_rows2<false>(s, ltw, tid);
    for (int i = tid; i < 512; i += 256){
        int l = i >> 8, e = i & 255;
        int line = line0 + l;
        int base = ((line >> 7) << 16) + ((line & 127) << 8);
        V[base + e] = s[l*256 + (e ^ 128)];      // store x-fftshifted
    }
}

// ---------------- final inverse x-FFT fused with |.|^2, crop x<128 ----------------
__global__ __launch_bounds__(256) void k_fft_x_inv_mag(const cpx* __restrict__ W,
                                                       float* __restrict__ out){
    __shared__ cpx s[2*256];
    __shared__ cpx ltw[256];
    int tid = threadIdx.x;
    ltw[tid] = g_tw[tid];
    int line0 = blockIdx.x << 1;
    for (int i = tid; i < 512; i += 256){
        int l = i >> 8, e = i & 255;
        int line = line0 + l;
        int base = ((line >> 7) << 16) + ((line & 127) << 8);
        s[l*256 + e] = W[base + e];
    }
    __syncthreads();
    fft_rows2<true>(s, ltw, tid);
    {
        int l = tid >> 7, e = tid & 127;
        int line = line0 + l;
        int z = line >> 7, y = line & 127;
        cpx v = s[l*256 + e];
        const float SC2 = (1.0f/33554432.0f)*(1.0f/33554432.0f);   // (1/(512*256*256))^2
        out[(z*128 + y)*128 + e] = (v.x*v.x + v.y*v.y)*SC2;
    }
}

// ---------------- FFT along y: 256 pts = 4 radix-4 DIF stages, tile 16 x, fixed z ----------------
// Forward path stores y-fftshifted (digit-reversed index ^2 reads bin k^128).
template<bool INV, bool HALF_IN, bool HALF_OUT>
__global__ __launch_bounds__(1024) void k_fft_y(cpx* __restrict__ V){
    __shared__ cpx s[256*16];                   // 32 KiB
    int tid = threadIdx.x;
    int z  = blockIdx.x >> 4;
    int x0 = (blockIdx.x & 15) << 4;
    int base = (z << 16) + x0;
    const int YIN = HALF_IN ? 128 : 256;
    for (int i = tid; i < YIN*16; i += 1024){
        int c = i & 15, e = i >> 4;
        s[e*16 + c] = V[base + (e << 8) + c];
    }
    if (HALF_IN){
        for (int i = tid; i < 128*16; i += 1024){
            int c = i & 15, e = (i >> 4) + 128;
            s[e*16 + c] = make_float2(0.0f, 0.0f);
        }
    }
    __syncthreads();
    int c = tid & 15, idx = tid >> 4;
    cpx x[4];
    {   // stage 0: stride 64, tw W_512^{2*j*r}
        int j = idx;
        #pragma unroll
        for (int t = 0; t < 4; ++t) x[t] = s[(j + (t << 6))*16 + c];
        dft4<INV>(x);
        #pragma unroll
        for (int r = 1; r < 4; ++r) x[r] = twmul<INV>(x[r], 2*j*r);
        #pragma unroll
        for (int r = 0; r < 4; ++r) s[(j + (r << 6))*16 + c] = x[r];
    }
    __syncthreads();
    {   // stage 1: stride 16, tw W_512^{8*j*r}
        int j = idx & 15, g = (idx >> 4) << 6;
        #pragma unroll
        for (int t = 0; t < 4; ++t) x[t] = s[(g + j + (t << 4))*16 + c];
        dft4<INV>(x);
        #pragma unroll
        for (int r = 1; r < 4; ++r) x[r] = twmul<INV>(x[r], 8*j*r);
        #pragma unroll
        for (int r = 0; r < 4; ++r) s[(g + j + (r << 4))*16 + c] = x[r];
    }
    __syncthreads();
    {   // stage 2: stride 4, tw W_512^{32*j*r}
        int j = idx & 3, g = (idx >> 2) << 4;
        #pragma unroll
        for (int t = 0; t < 4; ++t) x[t] = s[(g + j + (t << 2))*16 + c];
        dft4<INV>(x);
        #pragma unroll
        for (int r = 1; r < 4; ++r) x[r] = twmul<INV>(x[r], 32*j*r);
        #pragma unroll
        for (int r = 0; r < 4; ++r) s[(g + j + (r << 2))*16 + c] = x[r];
    }
    __syncthreads();
    {   // stage 3: stride 1, no twiddle
        int g = idx << 2;
        #pragma unroll
        for (int t = 0; t < 4; ++t) x[t] = s[(g + t)*16 + c];
        dft4<INV>(x);
        #pragma unroll
        for (int r = 0; r < 4; ++r) s[(g + r)*16 + c] = x[r];
    }
    __syncthreads();
    const int YOUT = HALF_OUT ? 128 : 256;
    for (int i = tid; i < YOUT*16; i += 1024){
        int cc = i & 15, e = i >> 4;
        int p = ((e & 3) << 6) | (((e >> 2) & 3) << 4) | (((e >> 4) & 3) << 2) | (e >> 6);
        if (!INV) p ^= 2;                        // forward: store bin e^128 at e (fftshift)
        V[base + (e << 8) + cc] = s[p*16 + cc];
    }
}

// ---------------- FFT along z: 512 pts = 3 radix-8 DIF stages, tile 16 x, fixed y ----------------
// Forward stores bins 0..255 at planes 256..511 (fftshifted upper half).
template<bool INV, bool HALF_IN, bool HALF_OUT>
__global__ __launch_bounds__(1024) void k_fft_z(cpx* __restrict__ V){
    __shared__ cpx s[512*16];                   // 64 KiB
    int tid = threadIdx.x;
    int y  = blockIdx.x >> 4;
    int x0 = (blockIdx.x & 15) << 4;
    int base = (y << 8) + x0;
    const int ZIN = HALF_IN ? 256 : 512;
    for (int i = tid; i < ZIN*16; i += 1024){
        int c = i & 15, e = i >> 4;
        s[e*16 + c] = V[base + (e << 16) + c];
    }
    if (HALF_IN){
        for (int i = tid; i < 256*16; i += 1024){
            int c = i & 15, e = (i >> 4) + 256;
            s[e*16 + c] = make_float2(0.0f, 0.0f);
        }
    }
    __syncthreads();
    int c = tid & 15, idx = tid >> 4;
    cpx x[8];
    {   // stage 0: stride 64, tw W_512^{j*r}
        int j = idx;
        #pragma unroll
        for (int t = 0; t < 8; ++t) x[t] = s[(j + (t << 6))*16 + c];
        dft8<INV>(x);
        #pragma unroll
        for (int r = 1; r < 8; ++r) x[r] = twmul<INV>(x[r], j*r);
        #pragma unroll
        for (int r = 0; r < 8; ++r) s[(j + (r << 6))*16 + c] = x[r];
    }
    __syncthreads();
    {   // stage 1: stride 8, tw W_512^{8*j*r}
        int j = idx & 7, g = (idx >> 3) << 6;
        #pragma unroll
        for (int t = 0; t < 8; ++t) x[t] = s[(g + j + (t << 3))*16 + c];
        dft8<INV>(x);
        #pragma unroll
        for (int r = 1; r < 8; ++r) x[r] = twmul<INV>(x[r], 8*j*r);
        #pragma unroll
        for (int r = 0; r < 8; ++r) s[(g + j + (r << 3))*16 + c] = x[r];
    }
    __syncthreads();
    {   // stage 2: stride 1, no twiddle
        int g = idx << 3;
        #pragma unroll
        for (int t = 0; t < 8; ++t) x[t] = s[(g + t)*16 + c];
        dft8<INV>(x);
        #pragma unroll
        for (int r = 0; r < 8; ++r) s[(g + r)*16 + c] = x[r];
    }
    __syncthreads();
    const int ZOUT = HALF_OUT ? 256 : 512;
    for (int i = tid; i < ZOUT*16; i += 1024){
        int cc = i & 15, e = i >> 4;
        int p = ((e & 7) << 6) | (e & 56) | (e >> 6);   // base-8 digit reversal of 9 bits
        int zo = INV ? e : (e + 256);
        V[base + (zo << 16) + cc] = s[p*16 + cc];
    }
}

// ---------------- Stolt resample: branchless, 4x float4 gathers, shifted source ----------------
// Source: planes 256..511 (shifted spectrum). Dest: planes 0..255, natural order.
__global__ __launch_bounds__(256) void k_resample(const cpx* __restrict__ V, cpx* __restrict__ W){
    int t = blockIdx.x*256 + threadIdx.x;        // 256*256*256 exactly
    int xd = t & 255, yd = (t >> 8) & 255, zd = t >> 16;
    if (zd == 0){ W[t] = make_float2(0.0f, 0.0f); return; }   // t[:, :M+1] = 0 plane
    int ys = (yd + 128) & 255, xs = (xd + 128) & 255;
    float gz = (float)zd*(1.0f/256.0f);          // zs-256 = zd
    float gy = (float)(ys - 128)*(1.0f/128.0f);
    float gx = (float)(xs - 128)*(1.0f/128.0f);
    float gzn = sqrtf(0.1024f*(gx*gx + gy*gy) + gz*gz);
    float ix = ((gx + 1.0f)*256.0f - 1.0f)*0.5f;
    float iy = ((gy + 1.0f)*256.0f - 1.0f)*0.5f;
    float iz = ((gzn + 1.0f)*512.0f - 1.0f)*0.5f;
    float fix = floorf(ix), fiy = floorf(iy), fiz = floorf(iz);
    int ix0 = (int)fix, iy0 = (int)fiy, iz0 = (int)fiz;
    float fx = ix - fix, fy = iy - fiy, fz = iz - fiz;
    // x: ix0 in [-1,254]; corner ix0+1 always valid; corner ix0 valid iff >=0
    int  xb  = ix0 > 0 ? ix0 : 0;
    bool xlo = (ix0 >= 0);
    float wx0 = xlo ? 1.0f - fx : 0.0f;
    float wx1 = fx;
    // y: iy0 in [-1,254]; same structure
    int  y0 = iy0 > 0 ? iy0 : 0, y1 = iy0 + 1;
    float wy0 = (iy0 >= 0) ? 1.0f - fy : 0.0f;
    float wy1 = fy;
    // z: iz0 in [256,536]; corners valid iff <=511; fold Jacobian scale into wz
    float sc = gz/(gzn + 1e-8f);
    int  z0 = iz0 < 511 ? iz0 : 511, z1 = (iz0 + 1) < 511 ? (iz0 + 1) : 511;
    float wz0 = (iz0     <= 511) ? (1.0f - fz)*sc : 0.0f;
    float wz1 = (iz0 + 1 <= 511) ? fz*sc : 0.0f;

    const char* Vb = (const char*)V;
    float4 a = *(const float4*)(Vb + (((size_t)(z0 << 16) + (y0 << 8) + xb) << 3));
    float4 b = *(const float4*)(Vb + (((size_t)(z0 << 16) + (y1 << 8) + xb) << 3));
    float4 c = *(const float4*)(Vb + (((size_t)(z1 << 16) + (y0 << 8) + xb) << 3));
    float4 d = *(const float4*)(Vb + (((size_t)(z1 << 16) + (y1 << 8) + xb) << 3));

    float w00 = wy0*wz0, w01 = wy1*wz0, w10 = wy0*wz1, w11 = wy1*wz1;
    float ar = 0.0f, ai = 0.0f;
    { float c1x = xlo ? a.z : a.x, c1y = xlo ? a.w : a.y;
      ar += (a.x*wx0 + c1x*wx1)*w00; ai += (a.y*wx0 + c1y*wx1)*w00; }
    { float c1x = xlo ? b.z : b.x, c1y = xlo ? b.w : b.y;
      ar += (b.x*wx0 + c1x*wx1)*w01; ai += (b.y*wx0 + c1y*wx1)*w01; }
    { float c1x = xlo ? c.z : c.x, c1y = xlo ? c.w : c.y;
      ar += (c.x*wx0 + c1x*wx1)*w10; ai += (c.y*wx0 + c1y*wx1)*w10; }
    { float c1x = xlo ? d.z : d.x, c1y = xlo ? d.w : d.y;
      ar += (d.x*wx0 + c1x*wx1)*w11; ai += (d.y*wx0 + c1y*wx1)*w11; }
    W[t] = make_float2(ar, ai);
}

extern "C" void kernel_launch(void* const* d_in, const int* in_sizes, int n_in,
                              void* d_out, int out_size, void* d_ws, size_t ws_size,
                              hipStream_t stream){
    const float* feat = (const float*)d_in[0];   // [1,1,256,128,128] f32; tbes=0, tens=256
    float* out = (float*)d_out;                  // [1,1,256,128,128] f32

    const size_t WS_NEED = (size_t)512*256*256*8;   // 268,435,456 B exactly
    if (ws_size < WS_NEED){
        hipMemsetAsync(d_out, 0, (size_t)out_size*sizeof(float), stream);
        return;
    }
    cpx* V = (cpx*)d_ws;

    k_tw<<<1, 512, 0, stream>>>();
    // forward FFT with fill fused; output stored fftshifted per axis
    k_fft_x_fill<<<16384, 256, 0, stream>>>(feat, V);               // lines z<256,y<128
    k_fft_y<false, true, false><<<4096, 1024, 0, stream>>>(V);      // z<256; y<128 in, full y out
    k_fft_z<false, true, true ><<<4096, 1024, 0, stream>>>(V);      // z<256 in -> planes 256..511
    // Stolt resample: reads planes 256..511, writes planes 0..255 (natural order)
    k_resample<<<65536, 256, 0, stream>>>(V, V);
    // inverse FFT + crop on planes 0..255
    k_fft_z<true, true, true ><<<4096, 1024, 0, stream>>>(V);       // z<256 in/out
    k_fft_y<true, false, true><<<4096, 1024, 0, stream>>>(V);       // full y in, y<128 out
    k_fft_x_inv_mag<<<16384, 256, 0, stream>>>(V, out);             // full x in, |.|^2, x<128
}

// Round 5
// 337.495 us; speedup vs baseline: 2.4085x; 1.1813x over previous
//
#include <hip/hip_runtime.h>

// LCT FK-migration: 3D FFT(512,256,256) -> Stolt trilinear resample -> 3D IFFT -> |.|^2
// Single 256 MiB workspace buffer V = [512][256][256] cpx, flat (z<<16)+(y<<8)+x.
// Forward spectrum is stored FFTSHIFTED (shift folded into forward output perms):
//   x,y: position (k+128)&255 ; z: bins 0..255 stored at planes 256..511.
// Stolt resample is FUSED into the inverse z-FFT: per (y, x-tile) block, gather the
// resampled z-line straight into LDS, run the inverse 512-pt FFT, write planes 0..255.
// Then inverse y (crop y<128) and inverse x fused with |.|^2 (crop x<128).

typedef float2 cpx;

__device__ float2 g_tw[512];   // exp(-2*pi*i*k/512), k in [0,512)

__device__ __forceinline__ cpx cadd(cpx a, cpx b){ return make_float2(a.x+b.x, a.y+b.y); }
__device__ __forceinline__ cpx csub(cpx a, cpx b){ return make_float2(a.x-b.x, a.y-b.y); }
__device__ __forceinline__ cpx cmul(cpx a, cpx b){ return make_float2(a.x*b.x - a.y*b.y, a.x*b.y + a.y*b.x); }

// ---------------- twiddle table (double-computed for accuracy) ----------------
__global__ void k_tw(){
    int j = threadIdx.x;                        // 512 threads
    double a = -2.0*3.14159265358979323846*(double)j/512.0;
    g_tw[j] = make_float2((float)cos(a), (float)sin(a));
}

template<bool INV>
__device__ __forceinline__ cpx twmul(cpx a, int k){
    cpx w = g_tw[k & 511];
    if (INV) w.y = -w.y;
    return cmul(a, w);
}

// ---------------- radix-4 DIF butterfly (in-register) ----------------
template<bool INV>
__device__ __forceinline__ void dft4(cpx* x){
    cpx e0 = cadd(x[0], x[2]), e1 = csub(x[0], x[2]);
    cpx o0 = cadd(x[1], x[3]), o1 = csub(x[1], x[3]);
    x[0] = cadd(e0, o0);
    x[2] = csub(e0, o0);
    if (!INV){ x[1] = make_float2(e1.x + o1.y, e1.y - o1.x);
               x[3] = make_float2(e1.x - o1.y, e1.y + o1.x); }
    else     { x[1] = make_float2(e1.x - o1.y, e1.y + o1.x);
               x[3] = make_float2(e1.x + o1.y, e1.y - o1.x); }
}

// ---------------- radix-8 DIF butterfly (in-register) ----------------
template<bool INV>
__device__ __forceinline__ void dft8(cpx* x){
    const float s = 0.70710678118654752440f;
    cpx e0 = cadd(x[0], x[4]), e2 = csub(x[0], x[4]);
    cpx e1 = cadd(x[2], x[6]), e3 = csub(x[2], x[6]);
    cpx E0 = cadd(e0, e1), E2 = csub(e0, e1);
    cpx E1, E3;
    if (!INV){ E1 = make_float2(e2.x + e3.y, e2.y - e3.x);
               E3 = make_float2(e2.x - e3.y, e2.y + e3.x); }
    else     { E1 = make_float2(e2.x - e3.y, e2.y + e3.x);
               E3 = make_float2(e2.x + e3.y, e2.y - e3.x); }
    cpx o0 = cadd(x[1], x[5]), o2 = csub(x[1], x[5]);
    cpx o1 = cadd(x[3], x[7]), o3 = csub(x[3], x[7]);
    cpx O0 = cadd(o0, o1), O2 = csub(o0, o1);
    cpx O1, O3;
    if (!INV){ O1 = make_float2(o2.x + o3.y, o2.y - o3.x);
               O3 = make_float2(o2.x - o3.y, o2.y + o3.x); }
    else     { O1 = make_float2(o2.x - o3.y, o2.y + o3.x);
               O3 = make_float2(o2.x + o3.y, o2.y - o3.x); }
    cpx W1, W2, W3;
    if (!INV){
        W1 = make_float2(s*(O1.x + O1.y), s*(O1.y - O1.x));
        W2 = make_float2(O2.y, -O2.x);
        W3 = make_float2(s*(O3.y - O3.x), -s*(O3.x + O3.y));
    } else {
        W1 = make_float2(s*(O1.x - O1.y), s*(O1.x + O1.y));
        W2 = make_float2(-O2.y, O2.x);
        W3 = make_float2(-s*(O3.x + O3.y), s*(O3.x - O3.y));
    }
    x[0] = cadd(E0, O0); x[4] = csub(E0, O0);
    x[1] = cadd(E1, W1); x[5] = csub(E1, W1);
    x[2] = cadd(E2, W2); x[6] = csub(E2, W2);
    x[3] = cadd(E3, W3); x[7] = csub(E3, W3);
}

// ---------------- in-LDS radix-2 FFT, layout s[line][elem], 2 lines of 256 ----------------
template<bool INV>
__device__ __forceinline__ void fft_rows2(cpx* s, const cpx* ltw, int tid){
    const int L2LEN = 8, LEN = 256;
    #pragma unroll
    for (int st = 0; st < L2LEN; ++st){
        int lh = L2LEN - 1 - st;
        int half = 1 << lh;
        int tws = 512 >> (L2LEN - st);
        int l  = tid >> (L2LEN - 1);
        int bf = tid & ((LEN/2) - 1);
        int j  = bf & (half - 1);
        int i0 = ((bf >> lh) << (lh + 1)) | j;
        cpx u = s[l*LEN + i0], v = s[l*LEN + i0 + half];
        cpx w = ltw[j*tws];
        if (INV) w.y = -w.y;
        s[l*LEN + i0]        = cadd(u, v);
        s[l*LEN + i0 + half] = cmul(csub(u, v), w);
        __syncthreads();
    }
    for (int i = tid; i < 2*LEN; i += 256){     // bit-reversal -> natural order
        int l = i >> L2LEN, k = i & (LEN - 1);
        int r = __brev((unsigned)k) >> (32 - L2LEN);
        if (r > k){ cpx a = s[l*LEN + k]; s[l*LEN + k] = s[l*LEN + r]; s[l*LEN + r] = a; }
    }
    __syncthreads();
}

// ---------------- inline Stolt gather for one (zd, yd, xd): shifted-source trilinear ----------------
__device__ __forceinline__ cpx stolt_gather(const cpx* __restrict__ V, int zd, int yd, int xd){
    if (zd == 0) return make_float2(0.0f, 0.0f);          // t[:, :M+1] = 0 plane
    int ys = (yd + 128) & 255, xs = (xd + 128) & 255;
    float gz = (float)zd*(1.0f/256.0f);
    float gy = (float)(ys - 128)*(1.0f/128.0f);
    float gx = (float)(xs - 128)*(1.0f/128.0f);
    float gzn = sqrtf(0.1024f*(gx*gx + gy*gy) + gz*gz);
    float ix = ((gx + 1.0f)*256.0f - 1.0f)*0.5f;
    float iy = ((gy + 1.0f)*256.0f - 1.0f)*0.5f;
    float iz = ((gzn + 1.0f)*512.0f - 1.0f)*0.5f;
    float fix = floorf(ix), fiy = floorf(iy), fiz = floorf(iz);
    int ix0 = (int)fix, iy0 = (int)fiy, iz0 = (int)fiz;
    float fx = ix - fix, fy = iy - fiy, fz = iz - fiz;
    int  xb  = ix0 > 0 ? ix0 : 0;
    bool xlo = (ix0 >= 0);
    float wx0 = xlo ? 1.0f - fx : 0.0f;
    float wx1 = fx;
    int  y0 = iy0 > 0 ? iy0 : 0, y1 = iy0 + 1;
    float wy0 = (iy0 >= 0) ? 1.0f - fy : 0.0f;
    float wy1 = fy;
    float sc = gz/(gzn + 1e-8f);
    int  z0 = iz0 < 511 ? iz0 : 511, z1 = (iz0 + 1) < 511 ? (iz0 + 1) : 511;
    float wz0 = (iz0     <= 511) ? (1.0f - fz)*sc : 0.0f;
    float wz1 = (iz0 + 1 <= 511) ? fz*sc : 0.0f;

    const char* Vb = (const char*)V;
    float4 a = *(const float4*)(Vb + (((size_t)(z0 << 16) + (y0 << 8) + xb) << 3));
    float4 b = *(const float4*)(Vb + (((size_t)(z0 << 16) + (y1 << 8) + xb) << 3));
    float4 c = *(const float4*)(Vb + (((size_t)(z1 << 16) + (y0 << 8) + xb) << 3));
    float4 d = *(const float4*)(Vb + (((size_t)(z1 << 16) + (y1 << 8) + xb) << 3));

    float w00 = wy0*wz0, w01 = wy1*wz0, w10 = wy0*wz1, w11 = wy1*wz1;
    float ar = 0.0f, ai = 0.0f;
    { float c1x = xlo ? a.z : a.x, c1y = xlo ? a.w : a.y;
      ar += (a.x*wx0 + c1x*wx1)*w00; ai += (a.y*wx0 + c1y*wx1)*w00; }
    { float c1x = xlo ? b.z : b.x, c1y = xlo ? b.w : b.y;
      ar += (b.x*wx0 + c1x*wx1)*w01; ai += (b.y*wx0 + c1y*wx1)*w01; }
    { float c1x = xlo ? c.z : c.x, c1y = xlo ? c.w : c.y;
      ar += (c.x*wx0 + c1x*wx1)*w10; ai += (c.y*wx0 + c1y*wx1)*w10; }
    { float c1x = xlo ? d.z : d.x, c1y = xlo ? d.w : d.y;
      ar += (d.x*wx0 + c1x*wx1)*w11; ai += (d.y*wx0 + c1y*wx1)*w11; }
    return make_float2(ar, ai);
}

// ---------------- forward x-FFT fused with fill (window+sqrt), shifted-x output ----------------
__global__ __launch_bounds__(256) void k_fft_x_fill(const float* __restrict__ feat, cpx* __restrict__ V){
    __shared__ cpx s[2*256];
    __shared__ cpx ltw[256];
    int tid = threadIdx.x;
    ltw[tid] = g_tw[tid];
    int line0 = blockIdx.x << 1;                 // line = z*128 + y, z<256, y<128
    {
        int l = tid >> 7, e = tid & 127;
        int line = line0 + l;
        int z = line >> 7;
        float g = (float)z*(1.0f/255.0f);
        float v = feat[(line << 7) + e]*g*g;     // feat[z][y][x]
        v = v > 0.0f ? sqrtf(v) : 0.0f;
        s[l*256 + e]       = make_float2(v, 0.0f);
        s[l*256 + e + 128] = make_float2(0.0f, 0.0f);
    }
    __syncthreads();
    fft_rows2<false>(s, ltw, tid);
    {   // store x-fftshifted, float4 (2 cpx) per thread
        int l = tid >> 7, f4c = tid & 127;
        int line = line0 + l;
        int base = ((line >> 7) << 16) + ((line & 127) << 8);
        ((float4*)(V + base))[f4c] = ((const float4*)(s + l*256))[f4c ^ 64];
    }
}

// ---------------- final inverse x-FFT fused with |.|^2, crop x<128 ----------------
__global__ __launch_bounds__(256) void k_fft_x_inv_mag(const cpx* __restrict__ W,
                                                       float* __restrict__ out){
    __shared__ cpx s[2*256];
    __shared__ cpx ltw[256];
    int tid = threadIdx.x;
    ltw[tid] = g_tw[tid];
    int line0 = blockIdx.x << 1;
    {   // load 2 cpx per thread
        int l = tid >> 7, f4c = tid & 127;
        int line = line0 + l;
        int base = ((line >> 7) << 16) + ((line & 127) << 8);
        ((float4*)(s + l*256))[f4c] = ((const float4*)(W + base))[f4c];
    }
    __syncthreads();
    fft_rows2<true>(s, ltw, tid);
    {
        int l = tid >> 7, e = tid & 127;
        int line = line0 + l;
        int z = line >> 7, y = line & 127;
        cpx v = s[l*256 + e];
        const float SC2 = (1.0f/33554432.0f)*(1.0f/33554432.0f);   // (1/(512*256*256))^2
        out[(z*128 + y)*128 + e] = (v.x*v.x + v.y*v.y)*SC2;
    }
}

// ---------------- FFT along y: 256 pts = 4 radix-4 DIF stages, tile 16 x, fixed z ----------------
// Forward path stores y-fftshifted (digit-reversed index ^2 reads bin k^128).
template<bool INV, bool HALF_IN, bool HALF_OUT>
__global__ __launch_bounds__(1024) void k_fft_y(cpx* __restrict__ V){
    __shared__ cpx s[256*16];                   // 32 KiB
    int tid = threadIdx.x;
    int z  = blockIdx.x >> 4;
    int x0 = (blockIdx.x & 15) << 4;
    int base = (z << 16) + x0;
    const int YIN = HALF_IN ? 128 : 256;
    for (int i = tid; i < YIN*8; i += 1024){     // float4: 8 units of 2 cpx per row
        int f4c = i & 7, e = i >> 3;
        ((float4*)(s + e*16))[f4c] = ((const float4*)(V + base + (e << 8)))[f4c];
    }
    if (HALF_IN){
        for (int i = tid; i < 128*16; i += 1024){
            int c = i & 15, e = (i >> 4) + 128;
            s[e*16 + c] = make_float2(0.0f, 0.0f);
        }
    }
    __syncthreads();
    int c = tid & 15, idx = tid >> 4;
    cpx x[4];
    {   // stage 0: stride 64, tw W_512^{2*j*r}
        int j = idx;
        #pragma unroll
        for (int t = 0; t < 4; ++t) x[t] = s[(j + (t << 6))*16 + c];
        dft4<INV>(x);
        #pragma unroll
        for (int r = 1; r < 4; ++r) x[r] = twmul<INV>(x[r], 2*j*r);
        #pragma unroll
        for (int r = 0; r < 4; ++r) s[(j + (r << 6))*16 + c] = x[r];
    }
    __syncthreads();
    {   // stage 1: stride 16, tw W_512^{8*j*r}
        int j = idx & 15, g = (idx >> 4) << 6;
        #pragma unroll
        for (int t = 0; t < 4; ++t) x[t] = s[(g + j + (t << 4))*16 + c];
        dft4<INV>(x);
        #pragma unroll
        for (int r = 1; r < 4; ++r) x[r] = twmul<INV>(x[r], 8*j*r);
        #pragma unroll
        for (int r = 0; r < 4; ++r) s[(g + j + (r << 4))*16 + c] = x[r];
    }
    __syncthreads();
    {   // stage 2: stride 4, tw W_512^{32*j*r}
        int j = idx & 3, g = (idx >> 2) << 4;
        #pragma unroll
        for (int t = 0; t < 4; ++t) x[t] = s[(g + j + (t << 2))*16 + c];
        dft4<INV>(x);
        #pragma unroll
        for (int r = 1; r < 4; ++r) x[r] = twmul<INV>(x[r], 32*j*r);
        #pragma unroll
        for (int r = 0; r < 4; ++r) s[(g + j + (r << 2))*16 + c] = x[r];
    }
    __syncthreads();
    {   // stage 3: stride 1, no twiddle
        int g = idx << 2;
        #pragma unroll
        for (int t = 0; t < 4; ++t) x[t] = s[(g + t)*16 + c];
        dft4<INV>(x);
        #pragma unroll
        for (int r = 0; r < 4; ++r) s[(g + r)*16 + c] = x[r];
    }
    __syncthreads();
    const int YOUT = HALF_OUT ? 128 : 256;
    for (int i = tid; i < YOUT*8; i += 1024){
        int f4c = i & 7, e = i >> 3;
        int p = ((e & 3) << 6) | (((e >> 2) & 3) << 4) | (((e >> 4) & 3) << 2) | (e >> 6);
        if (!INV) p ^= 2;                        // forward: store bin e^128 at e (fftshift)
        ((float4*)(V + base + (e << 8)))[f4c] = ((const float4*)(s + p*16))[f4c];
    }
}

// ---------------- forward FFT along z: 3 radix-8 DIF stages, tile 16 x, fixed y ----------------
// Reads planes 0..255 (zero-pads 256..511), stores bins 0..255 at planes 256..511 (shifted).
__global__ __launch_bounds__(1024) void k_fft_z_fwd(cpx* __restrict__ V){
    __shared__ cpx s[512*16];                   // 64 KiB
    int tid = threadIdx.x;
    int y  = blockIdx.x >> 4;
    int x0 = (blockIdx.x & 15) << 4;
    int base = (y << 8) + x0;
    for (int i = tid; i < 256*8; i += 1024){
        int f4c = i & 7, e = i >> 3;
        ((float4*)(s + e*16))[f4c] = ((const float4*)(V + base + (e << 16)))[f4c];
    }
    for (int i = tid; i < 256*16; i += 1024){
        int c = i & 15, e = (i >> 4) + 256;
        s[e*16 + c] = make_float2(0.0f, 0.0f);
    }
    __syncthreads();
    int c = tid & 15, idx = tid >> 4;
    cpx x[8];
    {   // stage 0: stride 64, tw W_512^{j*r}
        int j = idx;
        #pragma unroll
        for (int t = 0; t < 8; ++t) x[t] = s[(j + (t << 6))*16 + c];
        dft8<false>(x);
        #pragma unroll
        for (int r = 1; r < 8; ++r) x[r] = twmul<false>(x[r], j*r);
        #pragma unroll
        for (int r = 0; r < 8; ++r) s[(j + (r << 6))*16 + c] = x[r];
    }
    __syncthreads();
    {   // stage 1: stride 8, tw W_512^{8*j*r}
        int j = idx & 7, g = (idx >> 3) << 6;
        #pragma unroll
        for (int t = 0; t < 8; ++t) x[t] = s[(g + j + (t << 3))*16 + c];
        dft8<false>(x);
        #pragma unroll
        for (int r = 1; r < 8; ++r) x[r] = twmul<false>(x[r], 8*j*r);
        #pragma unroll
        for (int r = 0; r < 8; ++r) s[(g + j + (r << 3))*16 + c] = x[r];
    }
    __syncthreads();
    {   // stage 2: stride 1, no twiddle
        int g = idx << 3;
        #pragma unroll
        for (int t = 0; t < 8; ++t) x[t] = s[(g + t)*16 + c];
        dft8<false>(x);
        #pragma unroll
        for (int r = 0; r < 8; ++r) s[(g + r)*16 + c] = x[r];
    }
    __syncthreads();
    for (int i = tid; i < 256*8; i += 1024){
        int f4c = i & 7, e = i >> 3;
        int p = ((e & 7) << 6) | (e & 56) | (e >> 6);   // base-8 digit reversal of 9 bits
        ((float4*)(V + base + ((e + 256) << 16)))[f4c] = ((const float4*)(s + p*16))[f4c];
    }
}

// ---------------- FUSED: Stolt resample gather + inverse z-FFT, write planes 0..255 ----------------
// Reads planes 256..511 (scattered gathers), writes planes 0..255. Disjoint -> race-free.
__global__ __launch_bounds__(1024) void k_stolt_fftz_inv(const cpx* __restrict__ Vsrc, cpx* __restrict__ V){
    __shared__ cpx s[512*16];                   // 64 KiB
    int tid = threadIdx.x;
    int y  = blockIdx.x >> 4;
    int x0 = (blockIdx.x & 15) << 4;
    int base = (y << 8) + x0;
    // gather resampled z-line for zd in [0,256) straight into LDS
    for (int i = tid; i < 256*16; i += 1024){
        int c = i & 15, zd = i >> 4;
        s[zd*16 + c] = stolt_gather(Vsrc, zd, y, x0 + c);
    }
    for (int i = tid; i < 256*16; i += 1024){
        int c = i & 15, e = (i >> 4) + 256;
        s[e*16 + c] = make_float2(0.0f, 0.0f);
    }
    __syncthreads();
    int c = tid & 15, idx = tid >> 4;
    cpx x[8];
    {   // stage 0
        int j = idx;
        #pragma unroll
        for (int t = 0; t < 8; ++t) x[t] = s[(j + (t << 6))*16 + c];
        dft8<true>(x);
        #pragma unroll
        for (int r = 1; r < 8; ++r) x[r] = twmul<true>(x[r], j*r);
        #pragma unroll
        for (int r = 0; r < 8; ++r) s[(j + (r << 6))*16 + c] = x[r];
    }
    __syncthreads();
    {   // stage 1
        int j = idx & 7, g = (idx >> 3) << 6;
        #pragma unroll
        for (int t = 0; t < 8; ++t) x[t] = s[(g + j + (t << 3))*16 + c];
        dft8<true>(x);
        #pragma unroll
        for (int r = 1; r < 8; ++r) x[r] = twmul<true>(x[r], 8*j*r);
        #pragma unroll
        for (int r = 0; r < 8; ++r) s[(g + j + (r << 3))*16 + c] = x[r];
    }
    __syncthreads();
    {   // stage 2
        int g = idx << 3;
        #pragma unroll
        for (int t = 0; t < 8; ++t) x[t] = s[(g + t)*16 + c];
        dft8<true>(x);
        #pragma unroll
        for (int r = 0; r < 8; ++r) s[(g + r)*16 + c] = x[r];
    }
    __syncthreads();
    for (int i = tid; i < 256*8; i += 1024){
        int f4c = i & 7, e = i >> 3;
        int p = ((e & 7) << 6) | (e & 56) | (e >> 6);
        ((float4*)(V + base + (e << 16)))[f4c] = ((const float4*)(s + p*16))[f4c];
    }
}

extern "C" void kernel_launch(void* const* d_in, const int* in_sizes, int n_in,
                              void* d_out, int out_size, void* d_ws, size_t ws_size,
                              hipStream_t stream){
    const float* feat = (const float*)d_in[0];   // [1,1,256,128,128] f32; tbes=0, tens=256
    float* out = (float*)d_out;                  // [1,1,256,128,128] f32

    const size_t WS_NEED = (size_t)512*256*256*8;   // 268,435,456 B exactly
    if (ws_size < WS_NEED){
        hipMemsetAsync(d_out, 0, (size_t)out_size*sizeof(float), stream);
        return;
    }
    cpx* V = (cpx*)d_ws;

    k_tw<<<1, 512, 0, stream>>>();
    // forward FFT with fill fused; output stored fftshifted per axis
    k_fft_x_fill<<<16384, 256, 0, stream>>>(feat, V);               // lines z<256,y<128
    k_fft_y<false, true, false><<<4096, 1024, 0, stream>>>(V);      // z<256; y<128 in, full y out
    k_fft_z_fwd<<<4096, 1024, 0, stream>>>(V);                      // planes 0..255 -> 256..511
    // fused Stolt gather + inverse z-FFT: reads planes 256..511, writes 0..255
    k_stolt_fftz_inv<<<4096, 1024, 0, stream>>>(V, V);
    // inverse y + inverse x (+|.|^2) with crops
    k_fft_y<true, false, true><<<4096, 1024, 0, stream>>>(V);       // full y in, y<128 out
    k_fft_x_inv_mag<<<16384, 256, 0, stream>>>(V, out);             // full x in, |.|^2, x<128
}

// Round 6
// 305.849 us; speedup vs baseline: 2.6577x; 1.1035x over previous
//
#include <hip/hip_runtime.h>

// LCT FK-migration: 3D FFT(512,256,256) -> Stolt trilinear resample -> 3D IFFT -> |.|^2
// Single 256 MiB workspace buffer V = [512][256][256] cpx, flat (z<<16)+(y<<8)+x.
// Forward spectrum is stored FFTSHIFTED (shift folded into forward output perms):
//   x,y: position (k+128)&255 ; z: bins 0..255 stored at planes 256..511.
// KEY IDENTITY: grid_sample coords satisfy ix = xs-0.5, iy = ys-0.5 exactly (fx=fy=0.5),
// so x/y trilinear parts are fixed half-pixel blurs over adjacent shifted bins
// (zero boundary at shifted index 0). These blurs are folded into the forward x/y
// FFT stores. The fused Stolt+inverse-z kernel then does Z-ONLY interpolation
// (2 loads/point), inverse z-FFT in LDS, writes planes 0..255.
// Then inverse y (crop y<128) and inverse x fused with |.|^2 (crop x<128).

typedef float2 cpx;

__device__ float2 g_tw[512];   // exp(-2*pi*i*k/512), k in [0,512)

__device__ __forceinline__ cpx cadd(cpx a, cpx b){ return make_float2(a.x+b.x, a.y+b.y); }
__device__ __forceinline__ cpx csub(cpx a, cpx b){ return make_float2(a.x-b.x, a.y-b.y); }
__device__ __forceinline__ cpx cmul(cpx a, cpx b){ return make_float2(a.x*b.x - a.y*b.y, a.x*b.y + a.y*b.x); }

// ---------------- twiddle table (double-computed for accuracy) ----------------
__global__ void k_tw(){
    int j = threadIdx.x;                        // 512 threads
    double a = -2.0*3.14159265358979323846*(double)j/512.0;
    g_tw[j] = make_float2((float)cos(a), (float)sin(a));
}

template<bool INV>
__device__ __forceinline__ cpx twmul(cpx a, int k){
    cpx w = g_tw[k & 511];
    if (INV) w.y = -w.y;
    return cmul(a, w);
}

// ---------------- radix-4 DIF butterfly (in-register) ----------------
template<bool INV>
__device__ __forceinline__ void dft4(cpx* x){
    cpx e0 = cadd(x[0], x[2]), e1 = csub(x[0], x[2]);
    cpx o0 = cadd(x[1], x[3]), o1 = csub(x[1], x[3]);
    x[0] = cadd(e0, o0);
    x[2] = csub(e0, o0);
    if (!INV){ x[1] = make_float2(e1.x + o1.y, e1.y - o1.x);
               x[3] = make_float2(e1.x - o1.y, e1.y + o1.x); }
    else     { x[1] = make_float2(e1.x - o1.y, e1.y + o1.x);
               x[3] = make_float2(e1.x + o1.y, e1.y - o1.x); }
}

// ---------------- radix-8 DIF butterfly (in-register) ----------------
template<bool INV>
__device__ __forceinline__ void dft8(cpx* x){
    const float s = 0.70710678118654752440f;
    cpx e0 = cadd(x[0], x[4]), e2 = csub(x[0], x[4]);
    cpx e1 = cadd(x[2], x[6]), e3 = csub(x[2], x[6]);
    cpx E0 = cadd(e0, e1), E2 = csub(e0, e1);
    cpx E1, E3;
    if (!INV){ E1 = make_float2(e2.x + e3.y, e2.y - e3.x);
               E3 = make_float2(e2.x - e3.y, e2.y + e3.x); }
    else     { E1 = make_float2(e2.x - e3.y, e2.y + e3.x);
               E3 = make_float2(e2.x + e3.y, e2.y - e3.x); }
    cpx o0 = cadd(x[1], x[5]), o2 = csub(x[1], x[5]);
    cpx o1 = cadd(x[3], x[7]), o3 = csub(x[3], x[7]);
    cpx O0 = cadd(o0, o1), O2 = csub(o0, o1);
    cpx O1, O3;
    if (!INV){ O1 = make_float2(o2.x + o3.y, o2.y - o3.x);
               O3 = make_float2(o2.x - o3.y, o2.y + o3.x); }
    else     { O1 = make_float2(o2.x - o3.y, o2.y + o3.x);
               O3 = make_float2(o2.x + o3.y, o2.y - o3.x); }
    cpx W1, W2, W3;
    if (!INV){
        W1 = make_float2(s*(O1.x + O1.y), s*(O1.y - O1.x));
        W2 = make_float2(O2.y, -O2.x);
        W3 = make_float2(s*(O3.y - O3.x), -s*(O3.x + O3.y));
    } else {
        W1 = make_float2(s*(O1.x - O1.y), s*(O1.x + O1.y));
        W2 = make_float2(-O2.y, O2.x);
        W3 = make_float2(-s*(O3.x + O3.y), s*(O3.x - O3.y));
    }
    x[0] = cadd(E0, O0); x[4] = csub(E0, O0);
    x[1] = cadd(E1, W1); x[5] = csub(E1, W1);
    x[2] = cadd(E2, W2); x[6] = csub(E2, W2);
    x[3] = cadd(E3, W3); x[7] = csub(E3, W3);
}

// ---------------- in-LDS radix-2 FFT, layout s[line][elem], 2 lines of 256 ----------------
template<bool INV>
__device__ __forceinline__ void fft_rows2(cpx* s, const cpx* ltw, int tid){
    const int L2LEN = 8, LEN = 256;
    #pragma unroll
    for (int st = 0; st < L2LEN; ++st){
        int lh = L2LEN - 1 - st;
        int half = 1 << lh;
        int tws = 512 >> (L2LEN - st);
        int l  = tid >> (L2LEN - 1);
        int bf = tid & ((LEN/2) - 1);
        int j  = bf & (half - 1);
        int i0 = ((bf >> lh) << (lh + 1)) | j;
        cpx u = s[l*LEN + i0], v = s[l*LEN + i0 + half];
        cpx w = ltw[j*tws];
        if (INV) w.y = -w.y;
        s[l*LEN + i0]        = cadd(u, v);
        s[l*LEN + i0 + half] = cmul(csub(u, v), w);
        __syncthreads();
    }
    for (int i = tid; i < 2*LEN; i += 256){     // bit-reversal -> natural order
        int l = i >> L2LEN, k = i & (LEN - 1);
        int r = __brev((unsigned)k) >> (32 - L2LEN);
        if (r > k){ cpx a = s[l*LEN + k]; s[l*LEN + k] = s[l*LEN + r]; s[l*LEN + r] = a; }
    }
    __syncthreads();
}

// ---------------- forward x-FFT fused with fill; store x-fftshifted AND x-half-blurred ----------------
// Stored position p gets 0.5*(F_s[p-1] + F_s[p]),  F_s[q] = bin(q^128), F_s[-1] = 0.
__global__ __launch_bounds__(256) void k_fft_x_fill(const float* __restrict__ feat, cpx* __restrict__ V){
    __shared__ cpx s[2*256];
    __shared__ cpx ltw[256];
    int tid = threadIdx.x;
    ltw[tid] = g_tw[tid];
    int line0 = blockIdx.x << 1;                 // line = z*128 + y, z<256, y<128
    {
        int l = tid >> 7, e = tid & 127;
        int line = line0 + l;
        int z = line >> 7;
        float g = (float)z*(1.0f/255.0f);
        float v = feat[(line << 7) + e]*g*g;     // feat[z][y][x]
        v = v > 0.0f ? sqrtf(v) : 0.0f;
        s[l*256 + e]       = make_float2(v, 0.0f);
        s[l*256 + e + 128] = make_float2(0.0f, 0.0f);
    }
    __syncthreads();
    fft_rows2<false>(s, ltw, tid);
    {   // store blurred, float4 (positions 2f, 2f+1) per thread
        int l = tid >> 7, f = tid & 127;
        int line = line0 + l;
        int base = ((line >> 7) << 16) + ((line & 127) << 8);
        const float4* srow = (const float4*)(s + l*256);
        float4 A = srow[f ^ 64];                 // F_s[2f], F_s[2f+1]
        float4 B = make_float4(0.0f, 0.0f, 0.0f, 0.0f);
        if (f) B = srow[(f - 1) ^ 64];           // .zw = F_s[2f-1]
        float4 o;
        o.x = 0.5f*(B.z + A.x); o.y = 0.5f*(B.w + A.y);
        o.z = 0.5f*(A.x + A.z); o.w = 0.5f*(A.y + A.w);
        ((float4*)(V + base))[f] = o;
    }
}

// ---------------- final inverse x-FFT fused with |.|^2, crop x<128 ----------------
__global__ __launch_bounds__(256) void k_fft_x_inv_mag(const cpx* __restrict__ W,
                                                       float* __restrict__ out){
    __shared__ cpx s[2*256];
    __shared__ cpx ltw[256];
    int tid = threadIdx.x;
    ltw[tid] = g_tw[tid];
    int line0 = blockIdx.x << 1;
    {   // load 2 cpx per thread
        int l = tid >> 7, f4c = tid & 127;
        int line = line0 + l;
        int base = ((line >> 7) << 16) + ((line & 127) << 8);
        ((float4*)(s + l*256))[f4c] = ((const float4*)(W + base))[f4c];
    }
    __syncthreads();
    fft_rows2<true>(s, ltw, tid);
    {
        int l = tid >> 7, e = tid & 127;
        int line = line0 + l;
        int z = line >> 7, y = line & 127;
        cpx v = s[l*256 + e];
        const float SC2 = (1.0f/33554432.0f)*(1.0f/33554432.0f);   // (1/(512*256*256))^2
        out[(z*128 + y)*128 + e] = (v.x*v.x + v.y*v.y)*SC2;
    }
}

// ---------------- FFT along y: 256 pts = 4 radix-4 DIF stages, tile 16 x, fixed z ----------------
// Forward: store y-fftshifted AND y-half-blurred: pos e = 0.5*(F_s[e-1]+F_s[e]), F_s[-1]=0.
// Inverse: plain store, crop y<128.
template<bool INV, bool HALF_IN, bool HALF_OUT>
__global__ __launch_bounds__(1024) void k_fft_y(cpx* __restrict__ V){
    __shared__ cpx s[256*16];                   // 32 KiB
    int tid = threadIdx.x;
    int z  = blockIdx.x >> 4;
    int x0 = (blockIdx.x & 15) << 4;
    int base = (z << 16) + x0;
    const int YIN = HALF_IN ? 128 : 256;
    for (int i = tid; i < YIN*8; i += 1024){     // float4: 8 units of 2 cpx per row
        int f4c = i & 7, e = i >> 3;
        ((float4*)(s + e*16))[f4c] = ((const float4*)(V + base + (e << 8)))[f4c];
    }
    if (HALF_IN){
        for (int i = tid; i < 128*16; i += 1024){
            int c = i & 15, e = (i >> 4) + 128;
            s[e*16 + c] = make_float2(0.0f, 0.0f);
        }
    }
    __syncthreads();
    int c = tid & 15, idx = tid >> 4;
    cpx x[4];
    {   // stage 0: stride 64, tw W_512^{2*j*r}
        int j = idx;
        #pragma unroll
        for (int t = 0; t < 4; ++t) x[t] = s[(j + (t << 6))*16 + c];
        dft4<INV>(x);
        #pragma unroll
        for (int r = 1; r < 4; ++r) x[r] = twmul<INV>(x[r], 2*j*r);
        #pragma unroll
        for (int r = 0; r < 4; ++r) s[(j + (r << 6))*16 + c] = x[r];
    }
    __syncthreads();
    {   // stage 1: stride 16, tw W_512^{8*j*r}
        int j = idx & 15, g = (idx >> 4) << 6;
        #pragma unroll
        for (int t = 0; t < 4; ++t) x[t] = s[(g + j + (t << 4))*16 + c];
        dft4<INV>(x);
        #pragma unroll
        for (int r = 1; r < 4; ++r) x[r] = twmul<INV>(x[r], 8*j*r);
        #pragma unroll
        for (int r = 0; r < 4; ++r) s[(g + j + (r << 4))*16 + c] = x[r];
    }
    __syncthreads();
    {   // stage 2: stride 4, tw W_512^{32*j*r}
        int j = idx & 3, g = (idx >> 2) << 4;
        #pragma unroll
        for (int t = 0; t < 4; ++t) x[t] = s[(g + j + (t << 2))*16 + c];
        dft4<INV>(x);
        #pragma unroll
        for (int r = 1; r < 4; ++r) x[r] = twmul<INV>(x[r], 32*j*r);
        #pragma unroll
        for (int r = 0; r < 4; ++r) s[(g + j + (r << 2))*16 + c] = x[r];
    }
    __syncthreads();
    {   // stage 3: stride 1, no twiddle
        int g = idx << 2;
        #pragma unroll
        for (int t = 0; t < 4; ++t) x[t] = s[(g + t)*16 + c];
        dft4<INV>(x);
        #pragma unroll
        for (int r = 0; r < 4; ++r) s[(g + r)*16 + c] = x[r];
    }
    __syncthreads();
    const int YOUT = HALF_OUT ? 128 : 256;
    for (int i = tid; i < YOUT*8; i += 1024){
        int f4c = i & 7, e = i >> 3;
        if (!INV){
            // blurred shifted store: pos e = 0.5*(F_s[e-1] + F_s[e]); F_s[q] at row rev4(q)^2
            int p0 = (((e & 3) << 6) | (((e >> 2) & 3) << 4) | (((e >> 4) & 3) << 2) | (e >> 6)) ^ 2;
            float4 S0 = ((const float4*)(s + p0*16))[f4c];
            float4 S1 = make_float4(0.0f, 0.0f, 0.0f, 0.0f);
            if (e){
                int em = e - 1;
                int p1 = (((em & 3) << 6) | (((em >> 2) & 3) << 4) | (((em >> 4) & 3) << 2) | (em >> 6)) ^ 2;
                S1 = ((const float4*)(s + p1*16))[f4c];
            }
            float4 o;
            o.x = 0.5f*(S0.x + S1.x); o.y = 0.5f*(S0.y + S1.y);
            o.z = 0.5f*(S0.z + S1.z); o.w = 0.5f*(S0.w + S1.w);
            ((float4*)(V + base + (e << 8)))[f4c] = o;
        } else {
            int p = ((e & 3) << 6) | (((e >> 2) & 3) << 4) | (((e >> 4) & 3) << 2) | (e >> 6);
            ((float4*)(V + base + (e << 8)))[f4c] = ((const float4*)(s + p*16))[f4c];
        }
    }
}

// ---------------- forward FFT along z: 3 radix-8 DIF stages, tile 16 x, fixed y ----------------
// Reads planes 0..255 (zero-pads 256..511), stores bins 0..255 at planes 256..511 (shifted).
__global__ __launch_bounds__(1024) void k_fft_z_fwd(cpx* __restrict__ V){
    __shared__ cpx s[512*16];                   // 64 KiB
    int tid = threadIdx.x;
    int y  = blockIdx.x >> 4;
    int x0 = (blockIdx.x & 15) << 4;
    int base = (y << 8) + x0;
    for (int i = tid; i < 256*8; i += 1024){
        int f4c = i & 7, e = i >> 3;
        ((float4*)(s + e*16))[f4c] = ((const float4*)(V + base + (e << 16)))[f4c];
    }
    for (int i = tid; i < 256*16; i += 1024){
        int c = i & 15, e = (i >> 4) + 256;
        s[e*16 + c] = make_float2(0.0f, 0.0f);
    }
    __syncthreads();
    int c = tid & 15, idx = tid >> 4;
    cpx x[8];
    {   // stage 0: stride 64, tw W_512^{j*r}
        int j = idx;
        #pragma unroll
        for (int t = 0; t < 8; ++t) x[t] = s[(j + (t << 6))*16 + c];
        dft8<false>(x);
        #pragma unroll
        for (int r = 1; r < 8; ++r) x[r] = twmul<false>(x[r], j*r);
        #pragma unroll
        for (int r = 0; r < 8; ++r) s[(j + (r << 6))*16 + c] = x[r];
    }
    __syncthreads();
    {   // stage 1: stride 8, tw W_512^{8*j*r}
        int j = idx & 7, g = (idx >> 3) << 6;
        #pragma unroll
        for (int t = 0; t < 8; ++t) x[t] = s[(g + j + (t << 3))*16 + c];
        dft8<false>(x);
        #pragma unroll
        for (int r = 1; r < 8; ++r) x[r] = twmul<false>(x[r], 8*j*r);
        #pragma unroll
        for (int r = 0; r < 8; ++r) s[(g + j + (r << 3))*16 + c] = x[r];
    }
    __syncthreads();
    {   // stage 2: stride 1, no twiddle
        int g = idx << 3;
        #pragma unroll
        for (int t = 0; t < 8; ++t) x[t] = s[(g + t)*16 + c];
        dft8<false>(x);
        #pragma unroll
        for (int r = 0; r < 8; ++r) s[(g + r)*16 + c] = x[r];
    }
    __syncthreads();
    for (int i = tid; i < 256*8; i += 1024){
        int f4c = i & 7, e = i >> 3;
        int p = ((e & 7) << 6) | (e & 56) | (e >> 6);   // base-8 digit reversal of 9 bits
        ((float4*)(V + base + ((e + 256) << 16)))[f4c] = ((const float4*)(s + p*16))[f4c];
    }
}

// ---------------- FUSED: z-only Stolt gather + inverse z-FFT, write planes 0..255 ----------------
// Source (planes 256..511) already carries the x/y half-pixel blurs. Disjoint dest -> race-free.
__global__ __launch_bounds__(1024) void k_stolt_fftz_inv(const cpx* __restrict__ Vsrc, cpx* __restrict__ V){
    __shared__ cpx s[512*16];                   // 64 KiB
    int tid = threadIdx.x;
    int y  = blockIdx.x >> 4;
    int x0 = (blockIdx.x & 15) << 4;
    int base = (y << 8) + x0;
    // per-thread gather constants (c = tid&15 fixed across gather loop)
    int c = tid & 15;
    int xd = x0 + c;
    int xs = (xd + 128) & 255;
    int ys = (y + 128) & 255;
    float gx = (float)(xs - 128)*(1.0f/128.0f);
    float gy = (float)(ys - 128)*(1.0f/128.0f);
    float rxy = 0.1024f*(gx*gx + gy*gy);
    int srcoff = (ys << 8) + xs;
    // gather resampled z-line (z-interp only) for zd in [0,256) straight into LDS
    #pragma unroll 4
    for (int i = tid; i < 256*16; i += 1024){
        int zd = i >> 4;
        cpx r = make_float2(0.0f, 0.0f);
        if (zd){
            float gz = (float)zd*(1.0f/256.0f);
            float gzn = sqrtf(rxy + gz*gz);
            float iz = ((gzn + 1.0f)*512.0f - 1.0f)*0.5f;
            float fiz = floorf(iz);
            int iz0 = (int)fiz;
            float fz = iz - fiz;
            float sc = gz/(gzn + 1e-8f);
            int z0 = iz0 < 511 ? iz0 : 511;
            int z1 = (iz0 + 1) < 511 ? (iz0 + 1) : 511;
            float wz0 = (iz0     <= 511) ? (1.0f - fz)*sc : 0.0f;
            float wz1 = (iz0 + 1 <= 511) ? fz*sc : 0.0f;
            cpx a = Vsrc[((size_t)z0 << 16) + srcoff];
            cpx b = Vsrc[((size_t)z1 << 16) + srcoff];
            r.x = a.x*wz0 + b.x*wz1;
            r.y = a.y*wz0 + b.y*wz1;
        }
        s[i] = r;                                // s[zd*16 + c]
    }
    for (int i = tid; i < 256*16; i += 1024){
        int cc = i & 15, e = (i >> 4) + 256;
        s[e*16 + cc] = make_float2(0.0f, 0.0f);
    }
    __syncthreads();
    int idx = tid >> 4;
    cpx x[8];
    {   // stage 0
        int j = idx;
        #pragma unroll
        for (int t = 0; t < 8; ++t) x[t] = s[(j + (t << 6))*16 + c];
        dft8<true>(x);
        #pragma unroll
        for (int r = 1; r < 8; ++r) x[r] = twmul<true>(x[r], j*r);
        #pragma unroll
        for (int r = 0; r < 8; ++r) s[(j + (r << 6))*16 + c] = x[r];
    }
    __syncthreads();
    {   // stage 1
        int j = idx & 7, g = (idx >> 3) << 6;
        #pragma unroll
        for (int t = 0; t < 8; ++t) x[t] = s[(g + j + (t << 3))*16 + c];
        dft8<true>(x);
        #pragma unroll
        for (int r = 1; r < 8; ++r) x[r] = twmul<true>(x[r], 8*j*r);
        #pragma unroll
        for (int r = 0; r < 8; ++r) s[(g + j + (r << 3))*16 + c] = x[r];
    }
    __syncthreads();
    {   // stage 2
        int g = idx << 3;
        #pragma unroll
        for (int t = 0; t < 8; ++t) x[t] = s[(g + t)*16 + c];
        dft8<true>(x);
        #pragma unroll
        for (int r = 0; r < 8; ++r) s[(g + r)*16 + c] = x[r];
    }
    __syncthreads();
    for (int i = tid; i < 256*8; i += 1024){
        int f4c = i & 7, e = i >> 3;
        int p = ((e & 7) << 6) | (e & 56) | (e >> 6);
        ((float4*)(V + base + (e << 16)))[f4c] = ((const float4*)(s + p*16))[f4c];
    }
}

extern "C" void kernel_launch(void* const* d_in, const int* in_sizes, int n_in,
                              void* d_out, int out_size, void* d_ws, size_t ws_size,
                              hipStream_t stream){
    const float* feat = (const float*)d_in[0];   // [1,1,256,128,128] f32; tbes=0, tens=256
    float* out = (float*)d_out;                  // [1,1,256,128,128] f32

    const size_t WS_NEED = (size_t)512*256*256*8;   // 268,435,456 B exactly
    if (ws_size < WS_NEED){
        hipMemsetAsync(d_out, 0, (size_t)out_size*sizeof(float), stream);
        return;
    }
    cpx* V = (cpx*)d_ws;

    k_tw<<<1, 512, 0, stream>>>();
    // forward FFT with fill + x-blur fused; then y (+y-blur), z; all stored fftshifted
    k_fft_x_fill<<<16384, 256, 0, stream>>>(feat, V);               // lines z<256,y<128
    k_fft_y<false, true, false><<<4096, 1024, 0, stream>>>(V);      // z<256; y<128 in, full blurred y out
    k_fft_z_fwd<<<4096, 1024, 0, stream>>>(V);                      // planes 0..255 -> 256..511
    // fused z-only Stolt gather + inverse z-FFT: reads planes 256..511, writes 0..255
    k_stolt_fftz_inv<<<4096, 1024, 0, stream>>>(V, V);
    // inverse y + inverse x (+|.|^2) with crops
    k_fft_y<true, false, true><<<4096, 1024, 0, stream>>>(V);       // full y in, y<128 out
    k_fft_x_inv_mag<<<16384, 256, 0, stream>>>(V, out);             // full x in, |.|^2, x<128
}